// Round 1
// baseline (1525.038 us; speedup 1.0000x reference)
//
#include <hip/hip_runtime.h>
#include <hip/hip_bf16.h>

#define DD 64
#define GG 256

__device__ __forceinline__ float sigmf(float x){ return 1.f/(1.f+__expf(-x)); }
__device__ __forceinline__ float tanhfast(float x){ return 1.f - 2.f/(__expf(2.f*x)+1.f); }

// ---------------- init ----------------
__global__ void k_init_points(const float* __restrict__ emb, const float* __restrict__ xpr,
                              const int* __restrict__ y, const int* __restrict__ pt,
                              float* __restrict__ xp, float* __restrict__ xph, int NP){
  int i = blockIdx.x*256 + threadIdx.x;
  if (i >= NP*16) return;
  int p = i >> 4, q = i & 15;
  const float4* src = (pt[p]!=0) ? (const float4*)(emb + (size_t)y[p]*DD)
                                 : (const float4*)(xpr + (size_t)p*DD);
  ((float4*)xp)[i] = src[q];
  ((float4*)xph)[i] = make_float4(0.f,0.f,0.f,0.f);
}

__global__ void k_init_clauses(const float* __restrict__ Wci, const float* __restrict__ bci,
                               float* __restrict__ xc, float* __restrict__ xch, int NC){
  int i = blockIdx.x*256 + threadIdx.x;
  if (i >= NC*16) return;
  int q = i & 15;
  float4 v;
  v.x = Wci[q*4+0] + bci[q*4+0];
  v.y = Wci[q*4+1] + bci[q*4+1];
  v.z = Wci[q*4+2] + bci[q*4+2];
  v.w = Wci[q*4+3] + bci[q*4+3];
  ((float4*)xc)[i] = v;
  ((float4*)xch)[i] = make_float4(0.f,0.f,0.f,0.f);
}

__global__ void k_classify(const int* __restrict__ ct, int* __restrict__ tlist,
                           int* __restrict__ cnt, int NC){
  int c = blockIdx.x*256 + threadIdx.x;
  if (c >= NC) return;
  int tp = ct[c];
  int slot = atomicAdd(cnt + tp, 1);
  tlist[tp*NC + slot] = c;
}

// ---------------- clause LSTM (grouped GEMM by type) ----------------
// Block: one (type, 64-clause tile). gates[64cl][256g], K = 4*64 (gathered points) + 64 (h state)
__launch_bounds__(256)
__global__ void k_clause(const float* __restrict__ Wih, const float* __restrict__ Whh,
                         const float* __restrict__ bih, const float* __restrict__ bhh,
                         const float* __restrict__ xp,
                         float* __restrict__ xc, float* __restrict__ xch,
                         const int* __restrict__ p2c, const int* __restrict__ tlist,
                         const int* __restrict__ cnt, int NC){
  __shared__ __align__(16) float A[64][64];   // [k][clause]
  __shared__ __align__(16) float B[64][128];  // [k][gl], gl = d_loc*4 + q, g = q*64 + h*32 + d_loc
  const int tp = blockIdx.y;
  const int n = cnt[tp];
  const int base = blockIdx.x*64;
  if (base >= n) return;
  const int t = threadIdx.x;
  const int d_loc = t & 31;
  const int cg = t >> 5;
  const int s_cl = t >> 2;       // staging: clause row
  const int s_kq = t & 3;        // staging: 16-float chunk
  const int b_gl = t >> 1;       // staging: B column
  const int b_kh = t & 1;        // staging: k half

  int s_c = -1;
  if (base + s_cl < n) s_c = tlist[tp*NC + base + s_cl];

  float acc[2][8][4];
  #pragma unroll
  for (int h=0;h<2;h++)
    #pragma unroll
    for (int j=0;j<8;j++)
      #pragma unroll
      for (int q=0;q<4;q++) acc[h][j][q] = 0.f;

  for (int slot=0; slot<5; ++slot){
    if (slot==3 && tp==3) continue;   // midpoint zeros 4th point slot
    __syncthreads();
    // stage A
    {
      const float* src = nullptr;
      if (s_c >= 0){
        if (slot < 4){
          int p = p2c[s_c*4 + slot];
          src = xp + (size_t)p*DD + s_kq*16;
        } else {
          src = xc + (size_t)s_c*DD + s_kq*16;
        }
      }
      #pragma unroll
      for (int v4=0; v4<4; ++v4){
        float4 val = src ? ((const float4*)src)[v4] : make_float4(0.f,0.f,0.f,0.f);
        int k0 = s_kq*16 + v4*4;
        A[k0+0][s_cl]=val.x; A[k0+1][s_cl]=val.y; A[k0+2][s_cl]=val.z; A[k0+3][s_cl]=val.w;
      }
    }
    const float* Wbase; int ldw, kcol;
    if (slot < 4){ Wbase = Wih + (size_t)tp*GG*GG; ldw = GG; kcol = slot*64; }
    else         { Wbase = Whh + (size_t)tp*GG*DD; ldw = DD; kcol = 0; }
    #pragma unroll
    for (int h=0; h<2; ++h){
      if (h==1) __syncthreads();   // compute(h=0) done before B overwrite
      {
        int g = (b_gl&3)*64 + h*32 + (b_gl>>2);
        const float* wr = Wbase + (size_t)g*ldw + kcol + b_kh*32;
        #pragma unroll
        for (int v4=0; v4<8; ++v4){
          float4 val = ((const float4*)wr)[v4];
          int k0 = b_kh*32 + v4*4;
          B[k0+0][b_gl]=val.x; B[k0+1][b_gl]=val.y; B[k0+2][b_gl]=val.z; B[k0+3][b_gl]=val.w;
        }
      }
      __syncthreads();
      #pragma unroll 4
      for (int k=0;k<64;k++){
        float4 a0 = *(const float4*)&A[k][cg*8];
        float4 a1 = *(const float4*)&A[k][cg*8+4];
        float4 b  = *(const float4*)&B[k][d_loc*4];
        float av[8] = {a0.x,a0.y,a0.z,a0.w,a1.x,a1.y,a1.z,a1.w};
        #pragma unroll
        for (int j=0;j<8;j++){
          acc[h][j][0] += av[j]*b.x;
          acc[h][j][1] += av[j]*b.y;
          acc[h][j][2] += av[j]*b.z;
          acc[h][j][3] += av[j]*b.w;
        }
      }
    }
  }
  __syncthreads();
  // epilogue: LSTM nonlinearity, write h/c states
  float bi[2][4];
  #pragma unroll
  for (int h=0;h<2;h++)
    #pragma unroll
    for (int q=0;q<4;q++){
      int g = q*64 + h*32 + d_loc;
      bi[h][q] = bih[tp*GG+g] + bhh[tp*GG+g];
    }
  #pragma unroll
  for (int j=0;j<8;j++){
    int loc = cg*8 + j;
    if (base + loc >= n) break;
    int c = tlist[tp*NC + base + loc];
    #pragma unroll
    for (int h=0;h<2;h++){
      int d = h*32 + d_loc;
      float gi = acc[h][j][0] + bi[h][0];
      float gf = acc[h][j][1] + bi[h][1];
      float gn = acc[h][j][2] + bi[h][2];
      float go = acc[h][j][3] + bi[h][3];
      float cold = xch[(size_t)c*DD + d];
      float cn = sigmf(gf)*cold + sigmf(gi)*tanhfast(gn);
      float hn = sigmf(go)*tanhfast(cn);
      xc[(size_t)c*DD + d]  = hn;
      xch[(size_t)c*DD + d] = cn;
    }
  }
}

// ---------------- scatter: msg[p] += x_c[c] over incidence edges ----------------
__global__ void k_scatter(const float* __restrict__ xc, const int* __restrict__ p2c,
                          float* __restrict__ msg, int NE){
  int t = blockIdx.x*256 + threadIdx.x;
  if (t >= NE*16) return;
  int e = t >> 4, dq = t & 15;
  int c = e >> 2;
  float4 v = ((const float4*)xc)[(size_t)c*16 + dq];
  int p = p2c[e];
  float* m = msg + (size_t)p*DD + dq*4;
  atomicAdd(m+0, v.x); atomicAdd(m+1, v.y); atomicAdd(m+2, v.z); atomicAdd(m+3, v.w);
}

// ---------------- point LSTM ----------------
__launch_bounds__(256)
__global__ void k_point(const float* __restrict__ Wihu, const float* __restrict__ Whhu,
                        const float* __restrict__ bihu, const float* __restrict__ bhhu,
                        const float* __restrict__ msg, float* __restrict__ xp,
                        float* __restrict__ xph, const int* __restrict__ pt, int NP){
  __shared__ __align__(16) float A[64][64];
  __shared__ __align__(16) float B[64][128];
  const int base = blockIdx.x*64;
  const int t = threadIdx.x;
  const int d_loc = t & 31;
  const int cg = t >> 5;
  const int s_cl = t >> 2;
  const int s_kq = t & 3;
  const int b_gl = t >> 1;
  const int b_kh = t & 1;

  float acc[2][8][4];
  #pragma unroll
  for (int h=0;h<2;h++)
    #pragma unroll
    for (int j=0;j<8;j++)
      #pragma unroll
      for (int q=0;q<4;q++) acc[h][j][q] = 0.f;

  for (int slot=0; slot<2; ++slot){
    __syncthreads();
    {
      const float* srcb = (slot==0) ? msg : xp;
      const float* src = nullptr;
      if (base + s_cl < NP) src = srcb + (size_t)(base+s_cl)*DD + s_kq*16;
      #pragma unroll
      for (int v4=0; v4<4; ++v4){
        float4 val = src ? ((const float4*)src)[v4] : make_float4(0.f,0.f,0.f,0.f);
        int k0 = s_kq*16 + v4*4;
        A[k0+0][s_cl]=val.x; A[k0+1][s_cl]=val.y; A[k0+2][s_cl]=val.z; A[k0+3][s_cl]=val.w;
      }
    }
    const float* Wbase = (slot==0) ? Wihu : Whhu;  // [256][64]
    #pragma unroll
    for (int h=0; h<2; ++h){
      if (h==1) __syncthreads();
      {
        int g = (b_gl&3)*64 + h*32 + (b_gl>>2);
        const float* wr = Wbase + (size_t)g*DD + b_kh*32;
        #pragma unroll
        for (int v4=0; v4<8; ++v4){
          float4 val = ((const float4*)wr)[v4];
          int k0 = b_kh*32 + v4*4;
          B[k0+0][b_gl]=val.x; B[k0+1][b_gl]=val.y; B[k0+2][b_gl]=val.z; B[k0+3][b_gl]=val.w;
        }
      }
      __syncthreads();
      #pragma unroll 4
      for (int k=0;k<64;k++){
        float4 a0 = *(const float4*)&A[k][cg*8];
        float4 a1 = *(const float4*)&A[k][cg*8+4];
        float4 b  = *(const float4*)&B[k][d_loc*4];
        float av[8] = {a0.x,a0.y,a0.z,a0.w,a1.x,a1.y,a1.z,a1.w};
        #pragma unroll
        for (int j=0;j<8;j++){
          acc[h][j][0] += av[j]*b.x;
          acc[h][j][1] += av[j]*b.y;
          acc[h][j][2] += av[j]*b.z;
          acc[h][j][3] += av[j]*b.w;
        }
      }
    }
  }
  __syncthreads();
  float bi[2][4];
  #pragma unroll
  for (int h=0;h<2;h++)
    #pragma unroll
    for (int q=0;q<4;q++){
      int g = q*64 + h*32 + d_loc;
      bi[h][q] = bihu[g] + bhhu[g];
    }
  #pragma unroll
  for (int j=0;j<8;j++){
    int p = base + cg*8 + j;
    if (p >= NP) break;
    if (pt[p] != 0) continue;   // fixed points keep state
    #pragma unroll
    for (int h=0;h<2;h++){
      int d = h*32 + d_loc;
      float gi = acc[h][j][0] + bi[h][0];
      float gf = acc[h][j][1] + bi[h][1];
      float gn = acc[h][j][2] + bi[h][2];
      float go = acc[h][j][3] + bi[h][3];
      float cold = xph[(size_t)p*DD + d];
      float cn = sigmf(gf)*cold + sigmf(gi)*tanhfast(gn);
      float hn = sigmf(go)*tanhfast(cn);
      xp[(size_t)p*DD + d]  = hn;
      xph[(size_t)p*DD + d] = cn;
    }
  }
}

// ---------------- logits: out = x_p @ emb^T + cls_bias ----------------
__launch_bounds__(256)
__global__ void k_logits(const float* __restrict__ xp, const float* __restrict__ emb,
                         const float* __restrict__ cbias, float* __restrict__ out,
                         int NP, int V){
  __shared__ __align__(16) float A[64][64];    // [k][point]
  __shared__ __align__(16) float B[64][128];   // [k][v_local]
  const int pbase = blockIdx.x*64;
  const int vbase = blockIdx.y*128;
  const int t = threadIdx.x;
  const int vg = t & 31;
  const int pg = t >> 5;
  const int s_cl = t >> 2;
  const int s_kq = t & 3;
  const int b_vl = t >> 1;
  const int b_kh = t & 1;

  // stage A (x_p rows)
  {
    const float* src = (pbase + s_cl < NP) ? xp + (size_t)(pbase+s_cl)*DD + s_kq*16 : nullptr;
    #pragma unroll
    for (int v4=0; v4<4; ++v4){
      float4 val = src ? ((const float4*)src)[v4] : make_float4(0.f,0.f,0.f,0.f);
      int k0 = s_kq*16 + v4*4;
      A[k0+0][s_cl]=val.x; A[k0+1][s_cl]=val.y; A[k0+2][s_cl]=val.z; A[k0+3][s_cl]=val.w;
    }
  }
  // stage B (embedding rows, transposed)
  {
    int v = vbase + b_vl;
    const float* src = (v < V) ? emb + (size_t)v*DD + b_kh*32 : nullptr;
    #pragma unroll
    for (int v4=0; v4<8; ++v4){
      float4 val = src ? ((const float4*)src)[v4] : make_float4(0.f,0.f,0.f,0.f);
      int k0 = b_kh*32 + v4*4;
      B[k0+0][b_vl]=val.x; B[k0+1][b_vl]=val.y; B[k0+2][b_vl]=val.z; B[k0+3][b_vl]=val.w;
    }
  }
  __syncthreads();
  float acc[8][4];
  #pragma unroll
  for (int j=0;j<8;j++)
    #pragma unroll
    for (int q=0;q<4;q++) acc[j][q]=0.f;
  #pragma unroll 4
  for (int k=0;k<64;k++){
    float4 a0 = *(const float4*)&A[k][pg*8];
    float4 a1 = *(const float4*)&A[k][pg*8+4];
    float4 b  = *(const float4*)&B[k][vg*4];
    float av[8] = {a0.x,a0.y,a0.z,a0.w,a1.x,a1.y,a1.z,a1.w};
    #pragma unroll
    for (int j=0;j<8;j++){
      acc[j][0] += av[j]*b.x;
      acc[j][1] += av[j]*b.y;
      acc[j][2] += av[j]*b.z;
      acc[j][3] += av[j]*b.w;
    }
  }
  int v0 = vbase + vg*4;
  if (v0 + 3 >= V && v0 >= V) return;
  if (v0 + 3 < V){
    float4 cb = *(const float4*)(cbias + v0);
    #pragma unroll
    for (int j=0;j<8;j++){
      int p = pbase + pg*8 + j;
      if (p >= NP) break;
      float4 r;
      r.x = acc[j][0] + cb.x;
      r.y = acc[j][1] + cb.y;
      r.z = acc[j][2] + cb.z;
      r.w = acc[j][3] + cb.w;
      *(float4*)(out + (size_t)p*V + v0) = r;
    }
  } else {
    for (int j=0;j<8;j++){
      int p = pbase + pg*8 + j;
      if (p >= NP) break;
      for (int q=0;q<4 && v0+q<V;q++)
        out[(size_t)p*V + v0 + q] = acc[j][q] + cbias[v0+q];
    }
  }
}

extern "C" void kernel_launch(void* const* d_in, const int* in_sizes, int n_in,
                              void* d_out, int out_size, void* d_ws, size_t ws_size,
                              hipStream_t stream){
  const float* emb   = (const float*)d_in[0];
  const float* cbias = (const float*)d_in[1];
  const float* Wci   = (const float*)d_in[2];
  const float* bci   = (const float*)d_in[3];
  const float* Wihc  = (const float*)d_in[4];
  const float* Whhc  = (const float*)d_in[5];
  const float* bihc  = (const float*)d_in[6];
  const float* bhhc  = (const float*)d_in[7];
  const float* Wihu  = (const float*)d_in[8];
  const float* Whhu  = (const float*)d_in[9];
  const float* bihu  = (const float*)d_in[10];
  const float* bhhu  = (const float*)d_in[11];
  const float* xpr   = (const float*)d_in[12];
  const int* y    = (const int*)d_in[13];
  const int* pt   = (const int*)d_in[14];
  const int* ct   = (const int*)d_in[15];
  const int* p2c  = (const int*)d_in[16];
  const int NP = in_sizes[13];
  const int NC = in_sizes[15];
  const int V  = in_sizes[1];

  char* w = (char*)d_ws;
  auto alloc = [&](size_t bytes)->char*{ char* p = w; w += (bytes + 255) & ~255ull; return p; };
  float* xp   = (float*)alloc((size_t)NP*DD*4);
  float* xph  = (float*)alloc((size_t)NP*DD*4);
  float* msg  = (float*)alloc((size_t)NP*DD*4);
  float* xc   = (float*)alloc((size_t)NC*DD*4);
  float* xch  = (float*)alloc((size_t)NC*DD*4);
  int*   tlist= (int*)alloc((size_t)4*NC*4);
  int*   cnt  = (int*)alloc(256);

  hipMemsetAsync(cnt, 0, 16, stream);
  k_init_points<<<(NP*16+255)/256, 256, 0, stream>>>(emb, xpr, y, pt, xp, xph, NP);
  k_init_clauses<<<(NC*16+255)/256, 256, 0, stream>>>(Wci, bci, xc, xch, NC);
  k_classify<<<(NC+255)/256, 256, 0, stream>>>(ct, tlist, cnt, NC);

  const int ctiles = (NC+63)/64;
  const int num_iters = 2;  // fixed by the problem instance
  for (int it=0; it<num_iters; ++it){
    k_clause<<<dim3(ctiles,4), 256, 0, stream>>>(Wihc, Whhc, bihc, bhhc, xp, xc, xch,
                                                 p2c, tlist, cnt, NC);
    hipMemsetAsync(msg, 0, (size_t)NP*DD*4, stream);
    k_scatter<<<((size_t)NC*4*16+255)/256, 256, 0, stream>>>(xc, p2c, msg, NC*4);
    k_point<<<(NP+63)/64, 256, 0, stream>>>(Wihu, Whhu, bihu, bhhu, msg, xp, xph, pt, NP);
  }
  k_logits<<<dim3((NP+63)/64, (V+127)/128), 256, 0, stream>>>(xp, emb, cbias, (float*)d_out, NP, V);
}

// Round 2
// 1293.226 us; speedup vs baseline: 1.1793x; 1.1793x over previous
//
#include <hip/hip_runtime.h>
#include <hip/hip_bf16.h>

#define DD 64
#define GG 256

__device__ __forceinline__ float sigmf(float x){ return 1.f/(1.f+__expf(-x)); }
__device__ __forceinline__ float tanhfast(float x){ return 1.f - 2.f/(__expf(2.f*x)+1.f); }

// ---------------- init ----------------
__global__ void k_init_points(const float* __restrict__ emb, const float* __restrict__ xpr,
                              const int* __restrict__ y, const int* __restrict__ pt,
                              float* __restrict__ xp, float* __restrict__ xph, int NP){
  int i = blockIdx.x*256 + threadIdx.x;
  if (i >= NP*16) return;
  int p = i >> 4, q = i & 15;
  const float4* src = (pt[p]!=0) ? (const float4*)(emb + (size_t)y[p]*DD)
                                 : (const float4*)(xpr + (size_t)p*DD);
  ((float4*)xp)[i] = src[q];
  ((float4*)xph)[i] = make_float4(0.f,0.f,0.f,0.f);
}

__global__ void k_init_clauses(const float* __restrict__ Wci, const float* __restrict__ bci,
                               float* __restrict__ xc, float* __restrict__ xch, int NC){
  int i = blockIdx.x*256 + threadIdx.x;
  if (i >= NC*16) return;
  int q = i & 15;
  float4 v;
  v.x = Wci[q*4+0] + bci[q*4+0];
  v.y = Wci[q*4+1] + bci[q*4+1];
  v.z = Wci[q*4+2] + bci[q*4+2];
  v.w = Wci[q*4+3] + bci[q*4+3];
  ((float4*)xc)[i] = v;
  ((float4*)xch)[i] = make_float4(0.f,0.f,0.f,0.f);
}

// wave-aggregated classify: 1 atomic per (wave,type) instead of 1 per clause
__global__ void k_classify(const int* __restrict__ ct, int* __restrict__ tlist,
                           int* __restrict__ cnt, int NC){
  int c = blockIdx.x*256 + threadIdx.x;
  int lane = threadIdx.x & 63;
  int tp = (c < NC) ? ct[c] : -1;
  unsigned long long lt = (lane == 63) ? ~0ull >> 1 : ((1ull << lane) - 1ull);
  #pragma unroll
  for (int t=0; t<4; ++t){
    unsigned long long m = __ballot(tp==t);
    if (m == 0ull) continue;
    int nw = __popcll(m);
    int rank = __popcll(m & lt);
    int leader = __ffsll((long long)m) - 1;
    int base = 0;
    if (lane == leader) base = atomicAdd(cnt + t, nw);
    base = __shfl(base, leader);
    if (tp == t) tlist[t*NC + base + rank] = c;
  }
}

// ---------------- clause LSTM (grouped GEMM by type) ----------------
// Block: one (type, 64-clause tile). gates[64cl][256g], K = 4*64 (gathered points) + 64 (h state)
__launch_bounds__(256)
__global__ void k_clause(const float* __restrict__ Wih, const float* __restrict__ Whh,
                         const float* __restrict__ bih, const float* __restrict__ bhh,
                         const float* __restrict__ xp,
                         float* __restrict__ xc, float* __restrict__ xch,
                         const int* __restrict__ p2c, const int* __restrict__ tlist,
                         const int* __restrict__ cnt, int NC){
  __shared__ __align__(16) float A[64][64];   // [k][clause]
  __shared__ __align__(16) float B[64][128];  // [k][gl], gl = d_loc*4 + q, g = q*64 + h*32 + d_loc
  const int tp = blockIdx.y;
  const int n = cnt[tp];
  const int base = blockIdx.x*64;
  if (base >= n) return;
  const int t = threadIdx.x;
  const int d_loc = t & 31;
  const int cg = t >> 5;
  const int s_cl = t >> 2;       // staging: clause row
  const int s_kq = t & 3;        // staging: 16-float chunk
  const int b_gl = t >> 1;       // staging: B column
  const int b_kh = t & 1;        // staging: k half

  int s_c = -1;
  if (base + s_cl < n) s_c = tlist[tp*NC + base + s_cl];

  float acc[2][8][4];
  #pragma unroll
  for (int h=0;h<2;h++)
    #pragma unroll
    for (int j=0;j<8;j++)
      #pragma unroll
      for (int q=0;q<4;q++) acc[h][j][q] = 0.f;

  for (int slot=0; slot<5; ++slot){
    if (slot==3 && tp==3) continue;   // midpoint zeros 4th point slot
    __syncthreads();
    // stage A
    {
      const float* src = nullptr;
      if (s_c >= 0){
        if (slot < 4){
          int p = p2c[s_c*4 + slot];
          src = xp + (size_t)p*DD + s_kq*16;
        } else {
          src = xc + (size_t)s_c*DD + s_kq*16;
        }
      }
      #pragma unroll
      for (int v4=0; v4<4; ++v4){
        float4 val = src ? ((const float4*)src)[v4] : make_float4(0.f,0.f,0.f,0.f);
        int k0 = s_kq*16 + v4*4;
        A[k0+0][s_cl]=val.x; A[k0+1][s_cl]=val.y; A[k0+2][s_cl]=val.z; A[k0+3][s_cl]=val.w;
      }
    }
    const float* Wbase; int ldw, kcol;
    if (slot < 4){ Wbase = Wih + (size_t)tp*GG*GG; ldw = GG; kcol = slot*64; }
    else         { Wbase = Whh + (size_t)tp*GG*DD; ldw = DD; kcol = 0; }
    #pragma unroll
    for (int h=0; h<2; ++h){
      if (h==1) __syncthreads();   // compute(h=0) done before B overwrite
      {
        int g = (b_gl&3)*64 + h*32 + (b_gl>>2);
        const float* wr = Wbase + (size_t)g*ldw + kcol + b_kh*32;
        #pragma unroll
        for (int v4=0; v4<8; ++v4){
          float4 val = ((const float4*)wr)[v4];
          int k0 = b_kh*32 + v4*4;
          B[k0+0][b_gl]=val.x; B[k0+1][b_gl]=val.y; B[k0+2][b_gl]=val.z; B[k0+3][b_gl]=val.w;
        }
      }
      __syncthreads();
      #pragma unroll 4
      for (int k=0;k<64;k++){
        float4 a0 = *(const float4*)&A[k][cg*8];
        float4 a1 = *(const float4*)&A[k][cg*8+4];
        float4 b  = *(const float4*)&B[k][d_loc*4];
        float av[8] = {a0.x,a0.y,a0.z,a0.w,a1.x,a1.y,a1.z,a1.w};
        #pragma unroll
        for (int j=0;j<8;j++){
          acc[h][j][0] += av[j]*b.x;
          acc[h][j][1] += av[j]*b.y;
          acc[h][j][2] += av[j]*b.z;
          acc[h][j][3] += av[j]*b.w;
        }
      }
    }
  }
  __syncthreads();
  // epilogue: LSTM nonlinearity, write h/c states
  float bi[2][4];
  #pragma unroll
  for (int h=0;h<2;h++)
    #pragma unroll
    for (int q=0;q<4;q++){
      int g = q*64 + h*32 + d_loc;
      bi[h][q] = bih[tp*GG+g] + bhh[tp*GG+g];
    }
  #pragma unroll
  for (int j=0;j<8;j++){
    int loc = cg*8 + j;
    if (base + loc >= n) break;
    int c = tlist[tp*NC + base + loc];
    #pragma unroll
    for (int h=0;h<2;h++){
      int d = h*32 + d_loc;
      float gi = acc[h][j][0] + bi[h][0];
      float gf = acc[h][j][1] + bi[h][1];
      float gn = acc[h][j][2] + bi[h][2];
      float go = acc[h][j][3] + bi[h][3];
      float cold = xch[(size_t)c*DD + d];
      float cn = sigmf(gf)*cold + sigmf(gi)*tanhfast(gn);
      float hn = sigmf(go)*tanhfast(cn);
      xc[(size_t)c*DD + d]  = hn;
      xch[(size_t)c*DD + d] = cn;
    }
  }
}

// ---------------- scatter: msg[p] += x_c[c] over incidence edges ----------------
__global__ void k_scatter(const float* __restrict__ xc, const int* __restrict__ p2c,
                          float* __restrict__ msg, int NE){
  int t = blockIdx.x*256 + threadIdx.x;
  if (t >= NE*16) return;
  int e = t >> 4, dq = t & 15;
  int c = e >> 2;
  float4 v = ((const float4*)xc)[(size_t)c*16 + dq];
  int p = p2c[e];
  float* m = msg + (size_t)p*DD + dq*4;
  atomicAdd(m+0, v.x); atomicAdd(m+1, v.y); atomicAdd(m+2, v.z); atomicAdd(m+3, v.w);
}

// ---------------- point LSTM ----------------
__launch_bounds__(256)
__global__ void k_point(const float* __restrict__ Wihu, const float* __restrict__ Whhu,
                        const float* __restrict__ bihu, const float* __restrict__ bhhu,
                        const float* __restrict__ msg, float* __restrict__ xp,
                        float* __restrict__ xph, const int* __restrict__ pt, int NP){
  __shared__ __align__(16) float A[64][64];
  __shared__ __align__(16) float B[64][128];
  const int base = blockIdx.x*64;
  const int t = threadIdx.x;
  const int d_loc = t & 31;
  const int cg = t >> 5;
  const int s_cl = t >> 2;
  const int s_kq = t & 3;
  const int b_gl = t >> 1;
  const int b_kh = t & 1;

  float acc[2][8][4];
  #pragma unroll
  for (int h=0;h<2;h++)
    #pragma unroll
    for (int j=0;j<8;j++)
      #pragma unroll
      for (int q=0;q<4;q++) acc[h][j][q] = 0.f;

  for (int slot=0; slot<2; ++slot){
    __syncthreads();
    {
      const float* srcb = (slot==0) ? msg : xp;
      const float* src = nullptr;
      if (base + s_cl < NP) src = srcb + (size_t)(base+s_cl)*DD + s_kq*16;
      #pragma unroll
      for (int v4=0; v4<4; ++v4){
        float4 val = src ? ((const float4*)src)[v4] : make_float4(0.f,0.f,0.f,0.f);
        int k0 = s_kq*16 + v4*4;
        A[k0+0][s_cl]=val.x; A[k0+1][s_cl]=val.y; A[k0+2][s_cl]=val.z; A[k0+3][s_cl]=val.w;
      }
    }
    const float* Wbase = (slot==0) ? Wihu : Whhu;  // [256][64]
    #pragma unroll
    for (int h=0; h<2; ++h){
      if (h==1) __syncthreads();
      {
        int g = (b_gl&3)*64 + h*32 + (b_gl>>2);
        const float* wr = Wbase + (size_t)g*DD + b_kh*32;
        #pragma unroll
        for (int v4=0; v4<8; ++v4){
          float4 val = ((const float4*)wr)[v4];
          int k0 = b_kh*32 + v4*4;
          B[k0+0][b_gl]=val.x; B[k0+1][b_gl]=val.y; B[k0+2][b_gl]=val.z; B[k0+3][b_gl]=val.w;
        }
      }
      __syncthreads();
      #pragma unroll 4
      for (int k=0;k<64;k++){
        float4 a0 = *(const float4*)&A[k][cg*8];
        float4 a1 = *(const float4*)&A[k][cg*8+4];
        float4 b  = *(const float4*)&B[k][d_loc*4];
        float av[8] = {a0.x,a0.y,a0.z,a0.w,a1.x,a1.y,a1.z,a1.w};
        #pragma unroll
        for (int j=0;j<8;j++){
          acc[h][j][0] += av[j]*b.x;
          acc[h][j][1] += av[j]*b.y;
          acc[h][j][2] += av[j]*b.z;
          acc[h][j][3] += av[j]*b.w;
        }
      }
    }
  }
  __syncthreads();
  float bi[2][4];
  #pragma unroll
  for (int h=0;h<2;h++)
    #pragma unroll
    for (int q=0;q<4;q++){
      int g = q*64 + h*32 + d_loc;
      bi[h][q] = bihu[g] + bhhu[g];
    }
  #pragma unroll
  for (int j=0;j<8;j++){
    int p = base + cg*8 + j;
    if (p >= NP) break;
    if (pt[p] != 0) continue;   // fixed points keep state
    #pragma unroll
    for (int h=0;h<2;h++){
      int d = h*32 + d_loc;
      float gi = acc[h][j][0] + bi[h][0];
      float gf = acc[h][j][1] + bi[h][1];
      float gn = acc[h][j][2] + bi[h][2];
      float go = acc[h][j][3] + bi[h][3];
      float cold = xph[(size_t)p*DD + d];
      float cn = sigmf(gf)*cold + sigmf(gi)*tanhfast(gn);
      float hn = sigmf(go)*tanhfast(cn);
      xp[(size_t)p*DD + d]  = hn;
      xph[(size_t)p*DD + d] = cn;
    }
  }
}

// ---------------- logits: out = x_p @ emb^T + cls_bias ----------------
__launch_bounds__(256)
__global__ void k_logits(const float* __restrict__ xp, const float* __restrict__ emb,
                         const float* __restrict__ cbias, float* __restrict__ out,
                         int NP, int V){
  __shared__ __align__(16) float A[64][64];    // [k][point]
  __shared__ __align__(16) float B[64][128];   // [k][v_local]
  const int pbase = blockIdx.x*64;
  const int vbase = blockIdx.y*128;
  const int t = threadIdx.x;
  const int vg = t & 31;
  const int pg = t >> 5;
  const int s_cl = t >> 2;
  const int s_kq = t & 3;
  const int b_vl = t >> 1;
  const int b_kh = t & 1;

  // stage A (x_p rows)
  {
    const float* src = (pbase + s_cl < NP) ? xp + (size_t)(pbase+s_cl)*DD + s_kq*16 : nullptr;
    #pragma unroll
    for (int v4=0; v4<4; ++v4){
      float4 val = src ? ((const float4*)src)[v4] : make_float4(0.f,0.f,0.f,0.f);
      int k0 = s_kq*16 + v4*4;
      A[k0+0][s_cl]=val.x; A[k0+1][s_cl]=val.y; A[k0+2][s_cl]=val.z; A[k0+3][s_cl]=val.w;
    }
  }
  // stage B (embedding rows, transposed)
  {
    int v = vbase + b_vl;
    const float* src = (v < V) ? emb + (size_t)v*DD + b_kh*32 : nullptr;
    #pragma unroll
    for (int v4=0; v4<8; ++v4){
      float4 val = src ? ((const float4*)src)[v4] : make_float4(0.f,0.f,0.f,0.f);
      int k0 = b_kh*32 + v4*4;
      B[k0+0][b_vl]=val.x; B[k0+1][b_vl]=val.y; B[k0+2][b_vl]=val.z; B[k0+3][b_vl]=val.w;
    }
  }
  __syncthreads();
  float acc[8][4];
  #pragma unroll
  for (int j=0;j<8;j++)
    #pragma unroll
    for (int q=0;q<4;q++) acc[j][q]=0.f;
  #pragma unroll 4
  for (int k=0;k<64;k++){
    float4 a0 = *(const float4*)&A[k][pg*8];
    float4 a1 = *(const float4*)&A[k][pg*8+4];
    float4 b  = *(const float4*)&B[k][vg*4];
    float av[8] = {a0.x,a0.y,a0.z,a0.w,a1.x,a1.y,a1.z,a1.w};
    #pragma unroll
    for (int j=0;j<8;j++){
      acc[j][0] += av[j]*b.x;
      acc[j][1] += av[j]*b.y;
      acc[j][2] += av[j]*b.z;
      acc[j][3] += av[j]*b.w;
    }
  }
  int v0 = vbase + vg*4;
  if (v0 + 3 >= V && v0 >= V) return;
  if (v0 + 3 < V){
    float4 cb = *(const float4*)(cbias + v0);
    #pragma unroll
    for (int j=0;j<8;j++){
      int p = pbase + pg*8 + j;
      if (p >= NP) break;
      float4 r;
      r.x = acc[j][0] + cb.x;
      r.y = acc[j][1] + cb.y;
      r.z = acc[j][2] + cb.z;
      r.w = acc[j][3] + cb.w;
      *(float4*)(out + (size_t)p*V + v0) = r;
    }
  } else {
    for (int j=0;j<8;j++){
      int p = pbase + pg*8 + j;
      if (p >= NP) break;
      for (int q=0;q<4 && v0+q<V;q++)
        out[(size_t)p*V + v0 + q] = acc[j][q] + cbias[v0+q];
    }
  }
}

extern "C" void kernel_launch(void* const* d_in, const int* in_sizes, int n_in,
                              void* d_out, int out_size, void* d_ws, size_t ws_size,
                              hipStream_t stream){
  const float* emb   = (const float*)d_in[0];
  const float* cbias = (const float*)d_in[1];
  const float* Wci   = (const float*)d_in[2];
  const float* bci   = (const float*)d_in[3];
  const float* Wihc  = (const float*)d_in[4];
  const float* Whhc  = (const float*)d_in[5];
  const float* bihc  = (const float*)d_in[6];
  const float* bhhc  = (const float*)d_in[7];
  const float* Wihu  = (const float*)d_in[8];
  const float* Whhu  = (const float*)d_in[9];
  const float* bihu  = (const float*)d_in[10];
  const float* bhhu  = (const float*)d_in[11];
  const float* xpr   = (const float*)d_in[12];
  const int* y    = (const int*)d_in[13];
  const int* pt   = (const int*)d_in[14];
  const int* ct   = (const int*)d_in[15];
  const int* p2c  = (const int*)d_in[16];
  const int NP = in_sizes[13];
  const int NC = in_sizes[15];
  const int V  = in_sizes[1];

  char* w = (char*)d_ws;
  auto alloc = [&](size_t bytes)->char*{ char* p = w; w += (bytes + 255) & ~255ull; return p; };
  float* xp   = (float*)alloc((size_t)NP*DD*4);
  float* xph  = (float*)alloc((size_t)NP*DD*4);
  float* msg  = (float*)alloc((size_t)NP*DD*4);
  float* xc   = (float*)alloc((size_t)NC*DD*4);
  float* xch  = (float*)alloc((size_t)NC*DD*4);
  int*   tlist= (int*)alloc((size_t)4*NC*4);
  int*   cnt  = (int*)alloc(256);

  hipMemsetAsync(cnt, 0, 16, stream);
  k_init_points<<<(NP*16+255)/256, 256, 0, stream>>>(emb, xpr, y, pt, xp, xph, NP);
  k_init_clauses<<<(NC*16+255)/256, 256, 0, stream>>>(Wci, bci, xc, xch, NC);
  k_classify<<<(NC+255)/256, 256, 0, stream>>>(ct, tlist, cnt, NC);

  const int ctiles = (NC+63)/64;
  const int num_iters = 2;  // fixed by the problem instance
  for (int it=0; it<num_iters; ++it){
    k_clause<<<dim3(ctiles,4), 256, 0, stream>>>(Wihc, Whhc, bihc, bhhc, xp, xc, xch,
                                                 p2c, tlist, cnt, NC);
    hipMemsetAsync(msg, 0, (size_t)NP*DD*4, stream);
    k_scatter<<<((size_t)NC*4*16+255)/256, 256, 0, stream>>>(xc, p2c, msg, NC*4);
    k_point<<<(NP+63)/64, 256, 0, stream>>>(Wihu, Whhu, bihu, bhhu, msg, xp, xph, pt, NP);
  }
  k_logits<<<dim3((NP+63)/64, (V+127)/128), 256, 0, stream>>>(xp, emb, cbias, (float*)d_out, NP, V);
}

// Round 3
// 807.526 us; speedup vs baseline: 1.8885x; 1.6015x over previous
//
#include <hip/hip_runtime.h>
#include <hip/hip_bf16.h>

#define DD 64
#define GG 256

typedef __attribute__((ext_vector_type(8))) __bf16 bfrag;   // 8 bf16 = 4 VGPRs (gfx950 mfma operand)
typedef __attribute__((ext_vector_type(4))) float f32x4;

__device__ __forceinline__ float sigmf(float x){ return 1.f/(1.f+__expf(-x)); }
__device__ __forceinline__ float tanhfast(float x){ return 1.f - 2.f/(__expf(2.f*x)+1.f); }
__device__ __forceinline__ short bf16c(float f){
  __hip_bfloat16 h = __float2bfloat16(f);
  return *reinterpret_cast<short*>(&h);
}
__device__ __forceinline__ void cvt4(const float4 v, short* s){
  s[0]=bf16c(v.x); s[1]=bf16c(v.y); s[2]=bf16c(v.z); s[3]=bf16c(v.w);
}

// ---------------- init ----------------
__global__ void k_init_points(const float* __restrict__ emb, const float* __restrict__ xpr,
                              const int* __restrict__ y, const int* __restrict__ pt,
                              float* __restrict__ xp, float* __restrict__ xph, int NP){
  int i = blockIdx.x*256 + threadIdx.x;
  if (i >= NP*16) return;
  int p = i >> 4, q = i & 15;
  const float4* src = (pt[p]!=0) ? (const float4*)(emb + (size_t)y[p]*DD)
                                 : (const float4*)(xpr + (size_t)p*DD);
  ((float4*)xp)[i] = src[q];
  ((float4*)xph)[i] = make_float4(0.f,0.f,0.f,0.f);
}

__global__ void k_init_clauses(const float* __restrict__ Wci, const float* __restrict__ bci,
                               float* __restrict__ xc, float* __restrict__ xch, int NC){
  int i = blockIdx.x*256 + threadIdx.x;
  if (i >= NC*16) return;
  int q = i & 15;
  float4 v;
  v.x = Wci[q*4+0] + bci[q*4+0];
  v.y = Wci[q*4+1] + bci[q*4+1];
  v.z = Wci[q*4+2] + bci[q*4+2];
  v.w = Wci[q*4+3] + bci[q*4+3];
  ((float4*)xc)[i] = v;
  ((float4*)xch)[i] = make_float4(0.f,0.f,0.f,0.f);
}

// wave-aggregated classify: 1 atomic per (wave,type)
__global__ void k_classify(const int* __restrict__ ct, int* __restrict__ tlist,
                           int* __restrict__ cnt, int NC){
  int c = blockIdx.x*256 + threadIdx.x;
  int lane = threadIdx.x & 63;
  int tp = (c < NC) ? ct[c] : -1;
  unsigned long long lt = (lane == 63) ? ~0ull >> 1 : ((1ull << lane) - 1ull);
  #pragma unroll
  for (int t=0; t<4; ++t){
    unsigned long long m = __ballot(tp==t);
    if (m == 0ull) continue;
    int nw = __popcll(m);
    int rank = __popcll(m & lt);
    int leader = __ffsll((long long)m) - 1;
    int base = 0;
    if (lane == leader) base = atomicAdd(cnt + t, nw);
    base = __shfl(base, leader);
    if (tp == t) tlist[t*NC + base + rank] = c;
  }
}

// ---------------- weight/emb conversion to bf16 (once per launch) ----------------
// Wc_bf[tp][n][k] k<256 from Wihc, else Whhc (K=320). Wu_bf[n][k] k<64 Wihu else Whhu (K=128).
__global__ void k_cvt(const float* __restrict__ Wihc, const float* __restrict__ Whhc,
                      const float* __restrict__ Wihu, const float* __restrict__ Whhu,
                      const float* __restrict__ emb,
                      short* __restrict__ Wc_bf, short* __restrict__ Wu_bf,
                      short* __restrict__ emb_bf){
  int i = blockIdx.x*256 + threadIdx.x;
  if (i < 4*256*320){
    int k = i % 320; int nn = (i/320) % 256; int tp = i/(320*256);
    float v = (k < 256) ? Wihc[((size_t)tp*256+nn)*256 + k] : Whhc[((size_t)tp*256+nn)*64 + (k-256)];
    Wc_bf[i] = bf16c(v);
    return;
  }
  int j = i - 4*256*320;
  if (j < 256*128){
    int k = j % 128; int nn = j / 128;
    float v = (k < 64) ? Wihu[nn*64 + k] : Whhu[nn*64 + (k-64)];
    Wu_bf[j] = bf16c(v);
    return;
  }
  int e = j - 256*128;
  if (e < 400*64) emb_bf[e] = bf16c(emb[e]);
}

// ---------------- clause LSTM: MFMA grouped GEMM, M=64/block, K=320, N=256 ----------------
__launch_bounds__(256)
__global__ void k_clause_mfma(const short* __restrict__ Wc_bf,
                              const float* __restrict__ bih, const float* __restrict__ bhh,
                              const float* __restrict__ xp,
                              float* __restrict__ xc, float* __restrict__ xch,
                              const int* __restrict__ p2c, const int* __restrict__ tlist,
                              const int* __restrict__ cnt, int NC){
  __shared__ __align__(16) short As[64][328];   // [row][k], +8 pad -> row stride 4 banks
  __shared__ __align__(16) short Bs[256][40];   // [gate][k-local 32], +8 pad
  const int tp = blockIdx.y;
  const int n = cnt[tp];
  const int base = blockIdx.x*64;
  if (base >= n) return;
  const int t = threadIdx.x;
  // stage A: 4 threads/row, 16 floats each per slot (5 slots: 4 gathered points + h-state)
  {
    int row = t >> 2, ch = t & 3;
    int idx = base + row;
    int c = (idx < n) ? tlist[tp*NC + idx] : -1;
    #pragma unroll
    for (int slot=0; slot<5; ++slot){
      const float* src = nullptr;
      if (c >= 0){
        if (slot < 4){
          if (!(tp==3 && slot==3)){          // midpoint zeros 4th slot
            int p = p2c[c*4 + slot];
            src = xp + (size_t)p*DD + ch*16;
          }
        } else src = xc + (size_t)c*DD + ch*16;
      }
      union { short s[16]; bfrag v[2]; } u;
      #pragma unroll
      for (int f4=0; f4<4; ++f4){
        float4 val = src ? ((const float4*)src)[f4] : make_float4(0.f,0.f,0.f,0.f);
        cvt4(val, &u.s[f4*4]);
      }
      *(bfrag*)&As[row][slot*64 + ch*16 + 0] = u.v[0];
      *(bfrag*)&As[row][slot*64 + ch*16 + 8] = u.v[1];
    }
  }
  const int lane = t & 63, w = t >> 6;
  const int lr = lane & 15, lk = lane >> 4;
  f32x4 acc[16];
  #pragma unroll
  for (int i=0;i<16;i++) acc[i] = (f32x4){0.f,0.f,0.f,0.f};

  for (int ks=0; ks<10; ++ks){
    __syncthreads();
    { // stage B: thread t -> gate n=t, 32 bf16 of this k-step
      const bfrag* src = (const bfrag*)(Wc_bf + ((size_t)tp*256 + t)*320 + ks*32);
      #pragma unroll
      for (int cc=0;cc<4;cc++) *(bfrag*)&Bs[t][cc*8] = src[cc];
    }
    __syncthreads();
    bfrag a = *(const bfrag*)&As[w*16 + lr][ks*32 + lk*8];
    #pragma unroll
    for (int nt=0; nt<16; ++nt){
      bfrag b = *(const bfrag*)&Bs[nt*16 + lr][lk*8];
      acc[nt] = __builtin_amdgcn_mfma_f32_16x16x32_bf16(a, b, acc[nt], 0, 0, 0);
    }
  }
  // epilogue: lane holds gates[row=(lk*4+r)][col=nt*16+lr]; gate z*64+d -> nt=z*4+(d>>4)
  #pragma unroll
  for (int r=0; r<4; ++r){
    int idx = base + w*16 + lk*4 + r;
    if (idx >= n) continue;
    int c = tlist[tp*NC + idx];
    #pragma unroll
    for (int q=0; q<4; ++q){
      int d = lr + 16*q;
      float gi = acc[q][r]    + bih[tp*GG + d]       + bhh[tp*GG + d];
      float gf = acc[4+q][r]  + bih[tp*GG + 64 + d]  + bhh[tp*GG + 64 + d];
      float gn = acc[8+q][r]  + bih[tp*GG + 128 + d] + bhh[tp*GG + 128 + d];
      float go = acc[12+q][r] + bih[tp*GG + 192 + d] + bhh[tp*GG + 192 + d];
      float cold = xch[(size_t)c*DD + d];
      float cn = sigmf(gf)*cold + sigmf(gi)*tanhfast(gn);
      float hn = sigmf(go)*tanhfast(cn);
      xc[(size_t)c*DD + d]  = hn;
      xch[(size_t)c*DD + d] = cn;
    }
  }
}

// ---------------- scatter: msg[p] += x_c[c] over incidence edges ----------------
__global__ void k_scatter(const float* __restrict__ xc, const int* __restrict__ p2c,
                          float* __restrict__ msg, int NE){
  int t = blockIdx.x*256 + threadIdx.x;
  if (t >= NE*16) return;
  int e = t >> 4, dq = t & 15;
  int c = e >> 2;
  float4 v = ((const float4*)xc)[(size_t)c*16 + dq];
  int p = p2c[e];
  float* m = msg + (size_t)p*DD + dq*4;
  atomicAdd(m+0, v.x); atomicAdd(m+1, v.y); atomicAdd(m+2, v.z); atomicAdd(m+3, v.w);
}

// ---------------- point LSTM: MFMA, M=64/block, K=128 (msg|xp), N=256 ----------------
__launch_bounds__(256)
__global__ void k_point_mfma(const short* __restrict__ Wu_bf,
                             const float* __restrict__ bihu, const float* __restrict__ bhhu,
                             const float* __restrict__ msg, float* __restrict__ xp,
                             float* __restrict__ xph, const int* __restrict__ pt, int NP){
  __shared__ __align__(16) short As[64][136];
  __shared__ __align__(16) short Bs[256][40];
  const int t = threadIdx.x;
  const int base = blockIdx.x*64;
  { // stage A: 4 threads/row, 32 floats each; k<64 msg, k>=64 xp
    int row = t >> 2, ch = t & 3;
    int gr = base + row;
    bool ok = gr < NP;
    const float* src = (ch < 2) ? (msg + (size_t)gr*DD + ch*32)
                                : (xp  + (size_t)gr*DD + (ch-2)*32);
    #pragma unroll
    for (int half=0; half<2; ++half){
      union { short s[16]; bfrag v[2]; } u;
      #pragma unroll
      for (int f4=0; f4<4; ++f4){
        float4 val = ok ? ((const float4*)src)[half*4+f4] : make_float4(0.f,0.f,0.f,0.f);
        cvt4(val, &u.s[f4*4]);
      }
      *(bfrag*)&As[row][ch*32 + half*16 + 0] = u.v[0];
      *(bfrag*)&As[row][ch*32 + half*16 + 8] = u.v[1];
    }
  }
  const int lane = t & 63, w = t >> 6;
  const int lr = lane & 15, lk = lane >> 4;
  f32x4 acc[16];
  #pragma unroll
  for (int i=0;i<16;i++) acc[i] = (f32x4){0.f,0.f,0.f,0.f};

  for (int ks=0; ks<4; ++ks){
    __syncthreads();
    {
      const bfrag* src = (const bfrag*)(Wu_bf + t*128 + ks*32);
      #pragma unroll
      for (int cc=0;cc<4;cc++) *(bfrag*)&Bs[t][cc*8] = src[cc];
    }
    __syncthreads();
    bfrag a = *(const bfrag*)&As[w*16 + lr][ks*32 + lk*8];
    #pragma unroll
    for (int nt=0; nt<16; ++nt){
      bfrag b = *(const bfrag*)&Bs[nt*16 + lr][lk*8];
      acc[nt] = __builtin_amdgcn_mfma_f32_16x16x32_bf16(a, b, acc[nt], 0, 0, 0);
    }
  }
  #pragma unroll
  for (int r=0; r<4; ++r){
    int m = base + w*16 + lk*4 + r;
    if (m >= NP) continue;
    if (pt[m] != 0) continue;   // fixed points keep state
    #pragma unroll
    for (int q=0; q<4; ++q){
      int d = lr + 16*q;
      float gi = acc[q][r]    + bihu[d]       + bhhu[d];
      float gf = acc[4+q][r]  + bihu[64 + d]  + bhhu[64 + d];
      float gn = acc[8+q][r]  + bihu[128 + d] + bhhu[128 + d];
      float go = acc[12+q][r] + bihu[192 + d] + bhhu[192 + d];
      float cold = xph[(size_t)m*DD + d];
      float cn = sigmf(gf)*cold + sigmf(gi)*tanhfast(gn);
      float hn = sigmf(go)*tanhfast(cn);
      xp[(size_t)m*DD + d]  = hn;
      xph[(size_t)m*DD + d] = cn;
    }
  }
}

// ---------------- logits: MFMA, M=64/block, K=64, N=400 ----------------
__launch_bounds__(256)
__global__ void k_logits_mfma(const float* __restrict__ xp, const short* __restrict__ emb_bf,
                              const float* __restrict__ cbias, float* __restrict__ out,
                              int NP, int V){
  __shared__ __align__(16) short As[64][72];
  __shared__ __align__(16) short Bs[400][40];
  const int t = threadIdx.x;
  const int base = blockIdx.x*64;
  {
    int row = t >> 2, ch = t & 3;
    int gr = base + row;
    const float* src = (gr < NP) ? xp + (size_t)gr*DD + ch*16 : nullptr;
    union { short s[16]; bfrag v[2]; } u;
    #pragma unroll
    for (int f4=0; f4<4; ++f4){
      float4 val = src ? ((const float4*)src)[f4] : make_float4(0.f,0.f,0.f,0.f);
      cvt4(val, &u.s[f4*4]);
    }
    *(bfrag*)&As[row][ch*16 + 0] = u.v[0];
    *(bfrag*)&As[row][ch*16 + 8] = u.v[1];
  }
  const int lane = t & 63, w = t >> 6;
  const int lr = lane & 15, lk = lane >> 4;
  f32x4 acc[25];
  #pragma unroll
  for (int i=0;i<25;i++) acc[i] = (f32x4){0.f,0.f,0.f,0.f};
  for (int ks=0; ks<2; ++ks){
    __syncthreads();
    for (int nn = t; nn < 400; nn += 256){
      const bfrag* src = (const bfrag*)(emb_bf + nn*64 + ks*32);
      #pragma unroll
      for (int cc=0;cc<4;cc++) *(bfrag*)&Bs[nn][cc*8] = src[cc];
    }
    __syncthreads();
    bfrag a = *(const bfrag*)&As[w*16 + lr][ks*32 + lk*8];
    #pragma unroll
    for (int nt=0; nt<25; ++nt){
      bfrag b = *(const bfrag*)&Bs[nt*16 + lr][lk*8];
      acc[nt] = __builtin_amdgcn_mfma_f32_16x16x32_bf16(a, b, acc[nt], 0, 0, 0);
    }
  }
  #pragma unroll
  for (int r=0; r<4; ++r){
    int m = base + w*16 + lk*4 + r;
    if (m >= NP) continue;
    #pragma unroll
    for (int nt=0; nt<25; ++nt){
      int v = nt*16 + lr;
      out[(size_t)m*V + v] = acc[nt][r] + cbias[v];
    }
  }
}

extern "C" void kernel_launch(void* const* d_in, const int* in_sizes, int n_in,
                              void* d_out, int out_size, void* d_ws, size_t ws_size,
                              hipStream_t stream){
  const float* emb   = (const float*)d_in[0];
  const float* cbias = (const float*)d_in[1];
  const float* Wci   = (const float*)d_in[2];
  const float* bci   = (const float*)d_in[3];
  const float* Wihc  = (const float*)d_in[4];
  const float* Whhc  = (const float*)d_in[5];
  const float* bihc  = (const float*)d_in[6];
  const float* bhhc  = (const float*)d_in[7];
  const float* Wihu  = (const float*)d_in[8];
  const float* Whhu  = (const float*)d_in[9];
  const float* bihu  = (const float*)d_in[10];
  const float* bhhu  = (const float*)d_in[11];
  const float* xpr   = (const float*)d_in[12];
  const int* y    = (const int*)d_in[13];
  const int* pt   = (const int*)d_in[14];
  const int* ct   = (const int*)d_in[15];
  const int* p2c  = (const int*)d_in[16];
  const int NP = in_sizes[13];
  const int NC = in_sizes[15];
  const int V  = in_sizes[1];

  char* w = (char*)d_ws;
  auto alloc = [&](size_t bytes)->char*{ char* p = w; w += (bytes + 255) & ~255ull; return p; };
  float* xp   = (float*)alloc((size_t)NP*DD*4);
  float* xph  = (float*)alloc((size_t)NP*DD*4);
  float* msg  = (float*)alloc((size_t)NP*DD*4);
  float* xc   = (float*)alloc((size_t)NC*DD*4);
  float* xch  = (float*)alloc((size_t)NC*DD*4);
  int*   tlist= (int*)alloc((size_t)4*NC*4);
  int*   cnt  = (int*)alloc(256);
  short* Wc_bf = (short*)alloc((size_t)4*256*320*2);
  short* Wu_bf = (short*)alloc((size_t)256*128*2);
  short* emb_bf= (short*)alloc((size_t)400*64*2);

  hipMemsetAsync(cnt, 0, 16, stream);
  k_cvt<<<(4*256*320 + 256*128 + 400*64 + 255)/256, 256, 0, stream>>>(
      Wihc, Whhc, Wihu, Whhu, emb, Wc_bf, Wu_bf, emb_bf);
  k_init_points<<<(NP*16+255)/256, 256, 0, stream>>>(emb, xpr, y, pt, xp, xph, NP);
  k_init_clauses<<<(NC*16+255)/256, 256, 0, stream>>>(Wci, bci, xc, xch, NC);
  k_classify<<<(NC+255)/256, 256, 0, stream>>>(ct, tlist, cnt, NC);

  const int ctiles = (NC+63)/64;
  const int num_iters = 2;  // fixed by the problem instance
  for (int it=0; it<num_iters; ++it){
    k_clause_mfma<<<dim3(ctiles,4), 256, 0, stream>>>(Wc_bf, bihc, bhhc, xp, xc, xch,
                                                      p2c, tlist, cnt, NC);
    hipMemsetAsync(msg, 0, (size_t)NP*DD*4, stream);
    k_scatter<<<((size_t)NC*4*16+255)/256, 256, 0, stream>>>(xc, p2c, msg, NC*4);
    k_point_mfma<<<(NP+63)/64, 256, 0, stream>>>(Wu_bf, bihu, bhhu, msg, xp, xph, pt, NP);
  }
  k_logits_mfma<<<(NP+63)/64, 256, 0, stream>>>(xp, emb_bf, cbias, (float*)d_out, NP, V);
}

// Round 4
// 512.214 us; speedup vs baseline: 2.9773x; 1.5765x over previous
//
#include <hip/hip_runtime.h>
#include <hip/hip_bf16.h>

#define DD 64
#define GG 256

typedef __attribute__((ext_vector_type(8))) __bf16 bfrag;   // 8 bf16 = 4 VGPRs
typedef __attribute__((ext_vector_type(4))) float f32x4;

__device__ __forceinline__ float sigmf(float x){ return 1.f/(1.f+__expf(-x)); }
__device__ __forceinline__ float tanhfast(float x){ return 1.f - 2.f/(__expf(2.f*x)+1.f); }
__device__ __forceinline__ short bf16c(float f){
  __hip_bfloat16 h = __float2bfloat16(f);
  return *reinterpret_cast<short*>(&h);
}
__device__ __forceinline__ void cvt4(const float4 v, short* s){
  s[0]=bf16c(v.x); s[1]=bf16c(v.y); s[2]=bf16c(v.z); s[3]=bf16c(v.w);
}

// ---------------- init ----------------
__global__ void k_init_points(const float* __restrict__ emb, const float* __restrict__ xpr,
                              const int* __restrict__ y, const int* __restrict__ pt,
                              float* __restrict__ xp, float* __restrict__ xph, int NP){
  int i = blockIdx.x*256 + threadIdx.x;
  if (i >= NP*16) return;
  int p = i >> 4, q = i & 15;
  const float4* src = (pt[p]!=0) ? (const float4*)(emb + (size_t)y[p]*DD)
                                 : (const float4*)(xpr + (size_t)p*DD);
  ((float4*)xp)[i] = src[q];
  ((float4*)xph)[i] = make_float4(0.f,0.f,0.f,0.f);
}

__global__ void k_init_clauses(const float* __restrict__ Wci, const float* __restrict__ bci,
                               float* __restrict__ xc, float* __restrict__ xch, int NC){
  int i = blockIdx.x*256 + threadIdx.x;
  if (i >= NC*16) return;
  int q = i & 15;
  float4 v;
  v.x = Wci[q*4+0] + bci[q*4+0];
  v.y = Wci[q*4+1] + bci[q*4+1];
  v.z = Wci[q*4+2] + bci[q*4+2];
  v.w = Wci[q*4+3] + bci[q*4+3];
  ((float4*)xc)[i] = v;
  ((float4*)xch)[i] = make_float4(0.f,0.f,0.f,0.f);
}

// wave-aggregated classify: 1 atomic per (wave,type)
__global__ void k_classify(const int* __restrict__ ct, int* __restrict__ tlist,
                           int* __restrict__ cnt, int NC){
  int c = blockIdx.x*256 + threadIdx.x;
  int lane = threadIdx.x & 63;
  int tp = (c < NC) ? ct[c] : -1;
  unsigned long long lt = (lane == 63) ? ~0ull >> 1 : ((1ull << lane) - 1ull);
  #pragma unroll
  for (int t=0; t<4; ++t){
    unsigned long long m = __ballot(tp==t);
    if (m == 0ull) continue;
    int nw = __popcll(m);
    int rank = __popcll(m & lt);
    int leader = __ffsll((long long)m) - 1;
    int base = 0;
    if (lane == leader) base = atomicAdd(cnt + t, nw);
    base = __shfl(base, leader);
    if (tp == t) tlist[t*NC + base + rank] = c;
  }
}

// ---------------- CSR build: point -> incident clauses ----------------
__global__ void k_deg(const int* __restrict__ p2c, int* __restrict__ deg, int NE){
  int e = blockIdx.x*256 + threadIdx.x;
  if (e < NE) atomicAdd(deg + p2c[e], 1);
}
__global__ void k_blocksum(const int* __restrict__ deg, int* __restrict__ bsum, int NP){
  int i = blockIdx.x*256 + threadIdx.x;
  int v = (i < NP) ? deg[i] : 0;
  #pragma unroll
  for (int off=32; off>0; off>>=1) v += __shfl_down(v, off);
  __shared__ int ws[4];
  if ((threadIdx.x & 63) == 0) ws[threadIdx.x>>6] = v;
  __syncthreads();
  if (threadIdx.x == 0) bsum[blockIdx.x] = ws[0]+ws[1]+ws[2]+ws[3];
}
__global__ void k_scanblk(int* __restrict__ bsum, int NB){   // single block, 1024 thr
  __shared__ int s[1024];
  int tid = threadIdx.x;
  int v = (tid < NB) ? bsum[tid] : 0;
  s[tid] = v; __syncthreads();
  for (int off=1; off<1024; off<<=1){
    int tv = (tid >= off) ? s[tid-off] : 0;
    __syncthreads();
    s[tid] += tv;
    __syncthreads();
  }
  if (tid < NB) bsum[tid] = s[tid] - v;   // exclusive
}
__global__ void k_scanchunk(const int* __restrict__ deg, const int* __restrict__ bsum,
                            int* __restrict__ rowstart, int NP){
  __shared__ int s[256];
  int tid = threadIdx.x, i = blockIdx.x*256 + tid;
  int v = (i < NP) ? deg[i] : 0;
  s[tid] = v; __syncthreads();
  for (int off=1; off<256; off<<=1){
    int tv = (tid >= off) ? s[tid-off] : 0;
    __syncthreads();
    s[tid] += tv;
    __syncthreads();
  }
  if (i < NP) rowstart[i] = bsum[blockIdx.x] + s[tid] - v;
}
__global__ void k_fill(const int* __restrict__ p2c, const int* __restrict__ rowstart,
                       int* __restrict__ cursor, int* __restrict__ elist, int NE){
  int e = blockIdx.x*256 + threadIdx.x;
  if (e >= NE) return;
  int p = p2c[e];
  int pos = atomicAdd(cursor + p, 1);
  elist[rowstart[p] + pos] = e >> 2;   // clause index
}

// ---------------- weight/emb conversion to bf16 (once per launch) ----------------
__global__ void k_cvt(const float* __restrict__ Wihc, const float* __restrict__ Whhc,
                      const float* __restrict__ Wihu, const float* __restrict__ Whhu,
                      const float* __restrict__ emb,
                      short* __restrict__ Wc_bf, short* __restrict__ Wu_bf,
                      short* __restrict__ emb_bf){
  int i = blockIdx.x*256 + threadIdx.x;
  if (i < 4*256*320){
    int k = i % 320; int nn = (i/320) % 256; int tp = i/(320*256);
    float v = (k < 256) ? Wihc[((size_t)tp*256+nn)*256 + k] : Whhc[((size_t)tp*256+nn)*64 + (k-256)];
    Wc_bf[i] = bf16c(v);
    return;
  }
  int j = i - 4*256*320;
  if (j < 256*128){
    int k = j % 128; int nn = j / 128;
    float v = (k < 64) ? Wihu[nn*64 + k] : Whhu[nn*64 + (k-64)];
    Wu_bf[j] = bf16c(v);
    return;
  }
  int e = j - 256*128;
  if (e < 400*64) emb_bf[e] = bf16c(emb[e]);
}

// ---------------- clause LSTM: MFMA grouped GEMM, M=64/block, K=320, N=256 ----------------
__launch_bounds__(256)
__global__ void k_clause_mfma(const short* __restrict__ Wc_bf,
                              const float* __restrict__ bih, const float* __restrict__ bhh,
                              const float* __restrict__ xp,
                              float* __restrict__ xc, float* __restrict__ xch,
                              const int* __restrict__ p2c, const int* __restrict__ tlist,
                              const int* __restrict__ cnt, int NC){
  __shared__ __align__(16) short As[64][328];
  __shared__ __align__(16) short Bs[256][40];
  const int tp = blockIdx.y;
  const int n = cnt[tp];
  const int base = blockIdx.x*64;
  if (base >= n) return;
  const int t = threadIdx.x;
  {
    int row = t >> 2, ch = t & 3;
    int idx = base + row;
    int c = (idx < n) ? tlist[tp*NC + idx] : -1;
    #pragma unroll
    for (int slot=0; slot<5; ++slot){
      const float* src = nullptr;
      if (c >= 0){
        if (slot < 4){
          if (!(tp==3 && slot==3)){          // midpoint zeros 4th slot
            int p = p2c[c*4 + slot];
            src = xp + (size_t)p*DD + ch*16;
          }
        } else src = xc + (size_t)c*DD + ch*16;
      }
      union { short s[16]; bfrag v[2]; } u;
      #pragma unroll
      for (int f4=0; f4<4; ++f4){
        float4 val = src ? ((const float4*)src)[f4] : make_float4(0.f,0.f,0.f,0.f);
        cvt4(val, &u.s[f4*4]);
      }
      *(bfrag*)&As[row][slot*64 + ch*16 + 0] = u.v[0];
      *(bfrag*)&As[row][slot*64 + ch*16 + 8] = u.v[1];
    }
  }
  const int lane = t & 63, w = t >> 6;
  const int lr = lane & 15, lk = lane >> 4;
  f32x4 acc[16];
  #pragma unroll
  for (int i=0;i<16;i++) acc[i] = (f32x4){0.f,0.f,0.f,0.f};

  for (int ks=0; ks<10; ++ks){
    __syncthreads();
    {
      const bfrag* src = (const bfrag*)(Wc_bf + ((size_t)tp*256 + t)*320 + ks*32);
      #pragma unroll
      for (int cc=0;cc<4;cc++) *(bfrag*)&Bs[t][cc*8] = src[cc];
    }
    __syncthreads();
    bfrag a = *(const bfrag*)&As[w*16 + lr][ks*32 + lk*8];
    #pragma unroll
    for (int nt=0; nt<16; ++nt){
      bfrag b = *(const bfrag*)&Bs[nt*16 + lr][lk*8];
      acc[nt] = __builtin_amdgcn_mfma_f32_16x16x32_bf16(a, b, acc[nt], 0, 0, 0);
    }
  }
  #pragma unroll
  for (int r=0; r<4; ++r){
    int idx = base + w*16 + lk*4 + r;
    if (idx >= n) continue;
    int c = tlist[tp*NC + idx];
    #pragma unroll
    for (int q=0; q<4; ++q){
      int d = lr + 16*q;
      float gi = acc[q][r]    + bih[tp*GG + d]       + bhh[tp*GG + d];
      float gf = acc[4+q][r]  + bih[tp*GG + 64 + d]  + bhh[tp*GG + 64 + d];
      float gn = acc[8+q][r]  + bih[tp*GG + 128 + d] + bhh[tp*GG + 128 + d];
      float go = acc[12+q][r] + bih[tp*GG + 192 + d] + bhh[tp*GG + 192 + d];
      float cold = xch[(size_t)c*DD + d];
      float cn = sigmf(gf)*cold + sigmf(gi)*tanhfast(gn);
      float hn = sigmf(go)*tanhfast(cn);
      xc[(size_t)c*DD + d]  = hn;
      xch[(size_t)c*DD + d] = cn;
    }
  }
}

// ---------------- point LSTM: CSR-gathered msg fused; MFMA, K=128, N=256 ----------------
__launch_bounds__(256)
__global__ void k_point_mfma(const short* __restrict__ Wu_bf,
                             const float* __restrict__ bihu, const float* __restrict__ bhhu,
                             const float* __restrict__ xc,
                             const int* __restrict__ rowstart, const int* __restrict__ deg,
                             const int* __restrict__ elist,
                             float* __restrict__ xp, float* __restrict__ xph,
                             const int* __restrict__ pt, int NP){
  __shared__ __align__(16) short As[64][136];
  __shared__ __align__(16) short Bs[256][40];
  const int t = threadIdx.x;
  const int base = blockIdx.x*64;
  { // stage A: gather msg (k<64) from CSR, xp (k>=64); 4 threads/row, 16 dims each
    int row = t >> 2, ch = t & 3;
    int gr = base + row;
    bool ok = gr < NP;
    float s[16];
    #pragma unroll
    for (int z=0; z<16; ++z) s[z] = 0.f;
    if (ok){
      int rs = rowstart[gr], dg = deg[gr];
      for (int j=0; j<dg; ++j){
        int c = elist[rs + j];
        const float4* xcp = (const float4*)(xc + (size_t)c*DD + ch*16);
        #pragma unroll
        for (int f4=0; f4<4; ++f4){
          float4 v = xcp[f4];
          s[f4*4+0]+=v.x; s[f4*4+1]+=v.y; s[f4*4+2]+=v.z; s[f4*4+3]+=v.w;
        }
      }
    }
    union { short sh[16]; bfrag v[2]; } u;
    #pragma unroll
    for (int z=0; z<16; ++z) u.sh[z] = bf16c(s[z]);
    *(bfrag*)&As[row][ch*16 + 0] = u.v[0];
    *(bfrag*)&As[row][ch*16 + 8] = u.v[1];
    const float4* xpp = (const float4*)(xp + (size_t)gr*DD + ch*16);
    union { short sh[16]; bfrag v[2]; } u2;
    #pragma unroll
    for (int f4=0; f4<4; ++f4)
      cvt4(ok ? xpp[f4] : make_float4(0.f,0.f,0.f,0.f), &u2.sh[f4*4]);
    *(bfrag*)&As[row][64 + ch*16 + 0] = u2.v[0];
    *(bfrag*)&As[row][64 + ch*16 + 8] = u2.v[1];
  }
  const int lane = t & 63, w = t >> 6;
  const int lr = lane & 15, lk = lane >> 4;
  f32x4 acc[16];
  #pragma unroll
  for (int i=0;i<16;i++) acc[i] = (f32x4){0.f,0.f,0.f,0.f};

  for (int ks=0; ks<4; ++ks){
    __syncthreads();
    {
      const bfrag* src = (const bfrag*)(Wu_bf + t*128 + ks*32);
      #pragma unroll
      for (int cc=0;cc<4;cc++) *(bfrag*)&Bs[t][cc*8] = src[cc];
    }
    __syncthreads();
    bfrag a = *(const bfrag*)&As[w*16 + lr][ks*32 + lk*8];
    #pragma unroll
    for (int nt=0; nt<16; ++nt){
      bfrag b = *(const bfrag*)&Bs[nt*16 + lr][lk*8];
      acc[nt] = __builtin_amdgcn_mfma_f32_16x16x32_bf16(a, b, acc[nt], 0, 0, 0);
    }
  }
  #pragma unroll
  for (int r=0; r<4; ++r){
    int m = base + w*16 + lk*4 + r;
    if (m >= NP) continue;
    if (pt[m] != 0) continue;   // fixed points keep state
    #pragma unroll
    for (int q=0; q<4; ++q){
      int d = lr + 16*q;
      float gi = acc[q][r]    + bihu[d]       + bhhu[d];
      float gf = acc[4+q][r]  + bihu[64 + d]  + bhhu[64 + d];
      float gn = acc[8+q][r]  + bihu[128 + d] + bhhu[128 + d];
      float go = acc[12+q][r] + bihu[192 + d] + bhhu[192 + d];
      float cold = xph[(size_t)m*DD + d];
      float cn = sigmf(gf)*cold + sigmf(gi)*tanhfast(gn);
      float hn = sigmf(go)*tanhfast(cn);
      xp[(size_t)m*DD + d]  = hn;
      xph[(size_t)m*DD + d] = cn;
    }
  }
}

// ---------------- logits: MFMA, K=64, N=400; LDS-transposed float4 stores ----------------
#define ST 212
__launch_bounds__(256)
__global__ void k_logits_mfma(const float* __restrict__ xp, const short* __restrict__ emb_bf,
                              const float* __restrict__ cbias, float* __restrict__ out,
                              int NP, int V){
  __shared__ __align__(16) char smem[64*ST*4];   // 54272 B; staging (41216 B) overlaps
  short (*As)[72] = (short (*)[72])smem;
  short (*Bs)[40] = (short (*)[40])(smem + 64*72*2);
  float (*T)[ST]  = (float (*)[ST])smem;
  const int t = threadIdx.x;
  const int base = blockIdx.x*64;
  {
    int row = t >> 2, ch = t & 3;
    int gr = base + row;
    const float* src = (gr < NP) ? xp + (size_t)gr*DD + ch*16 : nullptr;
    union { short s[16]; bfrag v[2]; } u;
    #pragma unroll
    for (int f4=0; f4<4; ++f4){
      float4 val = src ? ((const float4*)src)[f4] : make_float4(0.f,0.f,0.f,0.f);
      cvt4(val, &u.s[f4*4]);
    }
    *(bfrag*)&As[row][ch*16 + 0] = u.v[0];
    *(bfrag*)&As[row][ch*16 + 8] = u.v[1];
  }
  const int lane = t & 63, w = t >> 6;
  const int lr = lane & 15, lk = lane >> 4;
  f32x4 acc[25];
  #pragma unroll
  for (int i=0;i<25;i++) acc[i] = (f32x4){0.f,0.f,0.f,0.f};
  for (int ks=0; ks<2; ++ks){
    __syncthreads();
    for (int nn = t; nn < 400; nn += 256){
      const bfrag* src = (const bfrag*)(emb_bf + nn*64 + ks*32);
      #pragma unroll
      for (int cc=0;cc<4;cc++) *(bfrag*)&Bs[nn][cc*8] = src[cc];
    }
    __syncthreads();
    bfrag a = *(const bfrag*)&As[w*16 + lr][ks*32 + lk*8];
    #pragma unroll
    for (int nt=0; nt<25; ++nt){
      bfrag b = *(const bfrag*)&Bs[nt*16 + lr][lk*8];
      acc[nt] = __builtin_amdgcn_mfma_f32_16x16x32_bf16(a, b, acc[nt], 0, 0, 0);
    }
  }
  // epilogue: transpose in LDS -> float4 stores. chunk0: nt 0..12 (208 cols), chunk1: nt 13..24 (192)
  const int row_t = t >> 2, q = t & 3;
  const int m = base + row_t;
  #pragma unroll
  for (int chunk=0; chunk<2; ++chunk){
    const int nt0 = chunk ? 13 : 0;
    const int nt1 = chunk ? 25 : 13;
    const int cb  = nt0*16;
    __syncthreads();
    #pragma unroll
    for (int nt=nt0; nt<nt1; ++nt){
      #pragma unroll
      for (int r=0; r<4; ++r)
        T[w*16 + lk*4 + r][nt*16 + lr - cb] = acc[nt][r];
    }
    __syncthreads();
    const int nk = chunk ? 12 : 13;
    if (m < NP){
      for (int k=0; k<nk; ++k){
        int c4 = q + 4*k;
        int col = cb + c4*4;
        float4 val = *(float4*)&T[row_t][c4*4];
        float4 cbv = *(const float4*)(cbias + col);
        val.x += cbv.x; val.y += cbv.y; val.z += cbv.z; val.w += cbv.w;
        *(float4*)(out + (size_t)m*V + col) = val;
      }
    }
  }
}

extern "C" void kernel_launch(void* const* d_in, const int* in_sizes, int n_in,
                              void* d_out, int out_size, void* d_ws, size_t ws_size,
                              hipStream_t stream){
  const float* emb   = (const float*)d_in[0];
  const float* cbias = (const float*)d_in[1];
  const float* Wci   = (const float*)d_in[2];
  const float* bci   = (const float*)d_in[3];
  const float* Wihc  = (const float*)d_in[4];
  const float* Whhc  = (const float*)d_in[5];
  const float* bihc  = (const float*)d_in[6];
  const float* bhhc  = (const float*)d_in[7];
  const float* Wihu  = (const float*)d_in[8];
  const float* Whhu  = (const float*)d_in[9];
  const float* bihu  = (const float*)d_in[10];
  const float* bhhu  = (const float*)d_in[11];
  const float* xpr   = (const float*)d_in[12];
  const int* y    = (const int*)d_in[13];
  const int* pt   = (const int*)d_in[14];
  const int* ct   = (const int*)d_in[15];
  const int* p2c  = (const int*)d_in[16];
  const int NP = in_sizes[13];
  const int NC = in_sizes[15];
  const int V  = in_sizes[1];
  const int NE = NC*4;

  char* w = (char*)d_ws;
  auto alloc = [&](size_t bytes)->char*{ char* p = w; w += (bytes + 255) & ~255ull; return p; };
  float* xp   = (float*)alloc((size_t)NP*DD*4);
  float* xph  = (float*)alloc((size_t)NP*DD*4);
  float* xc   = (float*)alloc((size_t)NC*DD*4);
  float* xch  = (float*)alloc((size_t)NC*DD*4);
  int*   tlist= (int*)alloc((size_t)4*NC*4);
  int*   cnt  = (int*)alloc(256);
  short* Wc_bf = (short*)alloc((size_t)4*256*320*2);
  short* Wu_bf = (short*)alloc((size_t)256*128*2);
  short* emb_bf= (short*)alloc((size_t)400*64*2);
  int*   deg     = (int*)alloc((size_t)NP*4);
  int*   rowstart= (int*)alloc((size_t)NP*4);
  int*   cursor  = (int*)alloc((size_t)NP*4);
  int*   elist   = (int*)alloc((size_t)NE*4);
  int*   bsum    = (int*)alloc(4096);

  const int NB = (NP + 255)/256;   // 782 <= 1024

  hipMemsetAsync(cnt, 0, 16, stream);
  hipMemsetAsync(deg, 0, (size_t)NP*4, stream);
  hipMemsetAsync(cursor, 0, (size_t)NP*4, stream);
  k_cvt<<<(4*256*320 + 256*128 + 400*64 + 255)/256, 256, 0, stream>>>(
      Wihc, Whhc, Wihu, Whhu, emb, Wc_bf, Wu_bf, emb_bf);
  k_init_points<<<(NP*16+255)/256, 256, 0, stream>>>(emb, xpr, y, pt, xp, xph, NP);
  k_init_clauses<<<(NC*16+255)/256, 256, 0, stream>>>(Wci, bci, xc, xch, NC);
  k_classify<<<(NC+255)/256, 256, 0, stream>>>(ct, tlist, cnt, NC);
  // CSR build (graph constant across iterations)
  k_deg<<<(NE+255)/256, 256, 0, stream>>>(p2c, deg, NE);
  k_blocksum<<<NB, 256, 0, stream>>>(deg, bsum, NP);
  k_scanblk<<<1, 1024, 0, stream>>>(bsum, NB);
  k_scanchunk<<<NB, 256, 0, stream>>>(deg, bsum, rowstart, NP);
  k_fill<<<(NE+255)/256, 256, 0, stream>>>(p2c, rowstart, cursor, elist, NE);

  const int ctiles = (NC+63)/64;
  const int num_iters = 2;  // fixed by the problem instance
  for (int it=0; it<num_iters; ++it){
    k_clause_mfma<<<dim3(ctiles,4), 256, 0, stream>>>(Wc_bf, bihc, bhhc, xp, xc, xch,
                                                      p2c, tlist, cnt, NC);
    k_point_mfma<<<(NP+63)/64, 256, 0, stream>>>(Wu_bf, bihu, bhhu, xc,
                                                 rowstart, deg, elist, xp, xph, pt, NP);
  }
  k_logits_mfma<<<(NP+63)/64, 256, 0, stream>>>(xp, emb_bf, cbias, (float*)d_out, NP, V);
}

// Round 5
// 509.851 us; speedup vs baseline: 2.9911x; 1.0046x over previous
//
#include <hip/hip_runtime.h>
#include <hip/hip_bf16.h>

#define DD 64
#define GG 256

typedef __attribute__((ext_vector_type(8))) __bf16 bfrag;   // 8 bf16 = 4 VGPRs
typedef __attribute__((ext_vector_type(4))) float f32x4;

__device__ __forceinline__ float sigmf(float x){ return 1.f/(1.f+__expf(-x)); }
__device__ __forceinline__ float tanhfast(float x){ return 1.f - 2.f/(__expf(2.f*x)+1.f); }
__device__ __forceinline__ short bf16c(float f){
  __hip_bfloat16 h = __float2bfloat16(f);
  return *reinterpret_cast<short*>(&h);
}
__device__ __forceinline__ void cvt4(const float4 v, short* s){
  s[0]=bf16c(v.x); s[1]=bf16c(v.y); s[2]=bf16c(v.z); s[3]=bf16c(v.w);
}

// ---------------- init ----------------
__global__ void k_init_points(const float* __restrict__ emb, const float* __restrict__ xpr,
                              const int* __restrict__ y, const int* __restrict__ pt,
                              float* __restrict__ xp, float* __restrict__ xph, int NP){
  int i = blockIdx.x*256 + threadIdx.x;
  if (i >= NP*16) return;
  int p = i >> 4, q = i & 15;
  const float4* src = (pt[p]!=0) ? (const float4*)(emb + (size_t)y[p]*DD)
                                 : (const float4*)(xpr + (size_t)p*DD);
  ((float4*)xp)[i] = src[q];
  ((float4*)xph)[i] = make_float4(0.f,0.f,0.f,0.f);
}

__global__ void k_init_clauses(const float* __restrict__ Wci, const float* __restrict__ bci,
                               float* __restrict__ xc, float* __restrict__ xch, int NC){
  int i = blockIdx.x*256 + threadIdx.x;
  if (i >= NC*16) return;
  int q = i & 15;
  float4 v;
  v.x = Wci[q*4+0] + bci[q*4+0];
  v.y = Wci[q*4+1] + bci[q*4+1];
  v.z = Wci[q*4+2] + bci[q*4+2];
  v.w = Wci[q*4+3] + bci[q*4+3];
  ((float4*)xc)[i] = v;
  ((float4*)xch)[i] = make_float4(0.f,0.f,0.f,0.f);
}

// wave-aggregated classify: 1 atomic per (wave,type)
__global__ void k_classify(const int* __restrict__ ct, int* __restrict__ tlist,
                           int* __restrict__ cnt, int NC){
  int c = blockIdx.x*256 + threadIdx.x;
  int lane = threadIdx.x & 63;
  int tp = (c < NC) ? ct[c] : -1;
  unsigned long long lt = (lane == 63) ? ~0ull >> 1 : ((1ull << lane) - 1ull);
  #pragma unroll
  for (int t=0; t<4; ++t){
    unsigned long long m = __ballot(tp==t);
    if (m == 0ull) continue;
    int nw = __popcll(m);
    int rank = __popcll(m & lt);
    int leader = __ffsll((long long)m) - 1;
    int base = 0;
    if (lane == leader) base = atomicAdd(cnt + t, nw);
    base = __shfl(base, leader);
    if (tp == t) tlist[t*NC + base + rank] = c;
  }
}

// wave-aggregated variable/fixed point compaction
__global__ void k_compact(const int* __restrict__ pt, int* __restrict__ vlist,
                          int* __restrict__ flist, int* __restrict__ cnt2, int NP){
  int p = blockIdx.x*256 + threadIdx.x;
  int lane = threadIdx.x & 63;
  int cls = (p < NP) ? ((pt[p]==0) ? 0 : 1) : -1;
  unsigned long long lt = (lane == 63) ? ~0ull >> 1 : ((1ull << lane) - 1ull);
  #pragma unroll
  for (int t=0; t<2; ++t){
    unsigned long long m = __ballot(cls==t);
    if (m == 0ull) continue;
    int nw = __popcll(m);
    int rank = __popcll(m & lt);
    int leader = __ffsll((long long)m) - 1;
    int base = 0;
    if (lane == leader) base = atomicAdd(cnt2 + t, nw);
    base = __shfl(base, leader);
    if (cls == t) (t ? flist : vlist)[base + rank] = p;
  }
}

// ---------------- CSR build: point -> incident clauses ----------------
__global__ void k_deg(const int* __restrict__ p2c, int* __restrict__ deg, int NE){
  int e = blockIdx.x*256 + threadIdx.x;
  if (e < NE) atomicAdd(deg + p2c[e], 1);
}
__global__ void k_blocksum(const int* __restrict__ deg, int* __restrict__ bsum, int NP){
  int i = blockIdx.x*256 + threadIdx.x;
  int v = (i < NP) ? deg[i] : 0;
  #pragma unroll
  for (int off=32; off>0; off>>=1) v += __shfl_down(v, off);
  __shared__ int ws[4];
  if ((threadIdx.x & 63) == 0) ws[threadIdx.x>>6] = v;
  __syncthreads();
  if (threadIdx.x == 0) bsum[blockIdx.x] = ws[0]+ws[1]+ws[2]+ws[3];
}
__global__ void k_scanblk(int* __restrict__ bsum, int NB){   // single block, 1024 thr
  __shared__ int s[1024];
  int tid = threadIdx.x;
  int v = (tid < NB) ? bsum[tid] : 0;
  s[tid] = v; __syncthreads();
  for (int off=1; off<1024; off<<=1){
    int tv = (tid >= off) ? s[tid-off] : 0;
    __syncthreads();
    s[tid] += tv;
    __syncthreads();
  }
  if (tid < NB) bsum[tid] = s[tid] - v;   // exclusive
}
__global__ void k_scanchunk(const int* __restrict__ deg, const int* __restrict__ bsum,
                            int* __restrict__ rowstart, int NP){
  __shared__ int s[256];
  int tid = threadIdx.x, i = blockIdx.x*256 + tid;
  int v = (i < NP) ? deg[i] : 0;
  s[tid] = v; __syncthreads();
  for (int off=1; off<256; off<<=1){
    int tv = (tid >= off) ? s[tid-off] : 0;
    __syncthreads();
    s[tid] += tv;
    __syncthreads();
  }
  if (i < NP) rowstart[i] = bsum[blockIdx.x] + s[tid] - v;
}
__global__ void k_fill(const int* __restrict__ p2c, const int* __restrict__ rowstart,
                       int* __restrict__ cursor, int* __restrict__ elist, int NE){
  int e = blockIdx.x*256 + threadIdx.x;
  if (e >= NE) return;
  int p = p2c[e];
  int pos = atomicAdd(cursor + p, 1);
  elist[rowstart[p] + pos] = e >> 2;   // clause index
}

// ---------------- weight/emb conversion to bf16 (once per launch) ----------------
__global__ void k_cvt(const float* __restrict__ Wihc, const float* __restrict__ Whhc,
                      const float* __restrict__ Wihu, const float* __restrict__ Whhu,
                      const float* __restrict__ emb,
                      short* __restrict__ Wc_bf, short* __restrict__ Wu_bf,
                      short* __restrict__ emb_bf){
  int i = blockIdx.x*256 + threadIdx.x;
  if (i < 4*256*320){
    int k = i % 320; int nn = (i/320) % 256; int tp = i/(320*256);
    float v = (k < 256) ? Wihc[((size_t)tp*256+nn)*256 + k] : Whhc[((size_t)tp*256+nn)*64 + (k-256)];
    Wc_bf[i] = bf16c(v);
    return;
  }
  int j = i - 4*256*320;
  if (j < 256*128){
    int k = j % 128; int nn = j / 128;
    float v = (k < 64) ? Wihu[nn*64 + k] : Whhu[nn*64 + (k-64)];
    Wu_bf[j] = bf16c(v);
    return;
  }
  int e = j - 256*128;
  if (e < 400*64) emb_bf[e] = bf16c(emb[e]);
}

// ---------------- clause LSTM: MFMA grouped GEMM, M=64/block, K=320, N=256 ----------------
__launch_bounds__(256)
__global__ void k_clause_mfma(const short* __restrict__ Wc_bf,
                              const float* __restrict__ bih, const float* __restrict__ bhh,
                              const float* __restrict__ xp,
                              float* __restrict__ xc, float* __restrict__ xch,
                              const int* __restrict__ p2c, const int* __restrict__ tlist,
                              const int* __restrict__ cnt, int NC){
  __shared__ __align__(16) short As[64][328];
  __shared__ __align__(16) short Bs[256][40];
  const int tp = blockIdx.y;
  const int n = cnt[tp];
  const int base = blockIdx.x*64;
  if (base >= n) return;
  const int t = threadIdx.x;
  {
    int row = t >> 2, ch = t & 3;
    int idx = base + row;
    int c = (idx < n) ? tlist[tp*NC + idx] : -1;
    #pragma unroll
    for (int slot=0; slot<5; ++slot){
      const float* src = nullptr;
      if (c >= 0){
        if (slot < 4){
          if (!(tp==3 && slot==3)){          // midpoint zeros 4th slot
            int p = p2c[c*4 + slot];
            src = xp + (size_t)p*DD + ch*16;
          }
        } else src = xc + (size_t)c*DD + ch*16;
      }
      union { short s[16]; bfrag v[2]; } u;
      #pragma unroll
      for (int f4=0; f4<4; ++f4){
        float4 val = src ? ((const float4*)src)[f4] : make_float4(0.f,0.f,0.f,0.f);
        cvt4(val, &u.s[f4*4]);
      }
      *(bfrag*)&As[row][slot*64 + ch*16 + 0] = u.v[0];
      *(bfrag*)&As[row][slot*64 + ch*16 + 8] = u.v[1];
    }
  }
  const int lane = t & 63, w = t >> 6;
  const int lr = lane & 15, lk = lane >> 4;
  f32x4 acc[16];
  #pragma unroll
  for (int i=0;i<16;i++) acc[i] = (f32x4){0.f,0.f,0.f,0.f};

  for (int ks=0; ks<10; ++ks){
    __syncthreads();
    {
      const bfrag* src = (const bfrag*)(Wc_bf + ((size_t)tp*256 + t)*320 + ks*32);
      #pragma unroll
      for (int cc=0;cc<4;cc++) *(bfrag*)&Bs[t][cc*8] = src[cc];
    }
    __syncthreads();
    bfrag a = *(const bfrag*)&As[w*16 + lr][ks*32 + lk*8];
    #pragma unroll
    for (int nt=0; nt<16; ++nt){
      bfrag b = *(const bfrag*)&Bs[nt*16 + lr][lk*8];
      acc[nt] = __builtin_amdgcn_mfma_f32_16x16x32_bf16(a, b, acc[nt], 0, 0, 0);
    }
  }
  #pragma unroll
  for (int r=0; r<4; ++r){
    int idx = base + w*16 + lk*4 + r;
    if (idx >= n) continue;
    int c = tlist[tp*NC + idx];
    #pragma unroll
    for (int q=0; q<4; ++q){
      int d = lr + 16*q;
      float gi = acc[q][r]    + bih[tp*GG + d]       + bhh[tp*GG + d];
      float gf = acc[4+q][r]  + bih[tp*GG + 64 + d]  + bhh[tp*GG + 64 + d];
      float gn = acc[8+q][r]  + bih[tp*GG + 128 + d] + bhh[tp*GG + 128 + d];
      float go = acc[12+q][r] + bih[tp*GG + 192 + d] + bhh[tp*GG + 192 + d];
      float cold = xch[(size_t)c*DD + d];
      float cn = sigmf(gf)*cold + sigmf(gi)*tanhfast(gn);
      float hn = sigmf(go)*tanhfast(cn);
      xc[(size_t)c*DD + d]  = hn;
      xch[(size_t)c*DD + d] = cn;
    }
  }
}

// ---------------- point LSTM: variable points only; CSR gather fused; K=128, N=256 ----------------
__launch_bounds__(256)
__global__ void k_point_mfma(const short* __restrict__ Wu_bf,
                             const float* __restrict__ bihu, const float* __restrict__ bhhu,
                             const float* __restrict__ xc,
                             const int* __restrict__ rowstart, const int* __restrict__ deg,
                             const int* __restrict__ elist, const int* __restrict__ vlist,
                             const int* __restrict__ nvp,
                             float* __restrict__ xp, float* __restrict__ xph, int NP){
  const int nv = nvp[0];
  const int base = blockIdx.x*64;
  if (base >= nv) return;
  __shared__ __align__(16) short As[64][136];
  __shared__ __align__(16) short Bs[256][40];
  const int t = threadIdx.x;
  { // stage A: gather msg (k<64) from CSR, xp (k>=64); 4 threads/row, 16 dims each
    int row = t >> 2, ch = t & 3;
    int idx = base + row;
    int gr = (idx < nv) ? vlist[idx] : -1;
    bool ok = gr >= 0;
    float s[16];
    #pragma unroll
    for (int z=0; z<16; ++z) s[z] = 0.f;
    if (ok){
      int rs = rowstart[gr], dg = deg[gr];
      for (int j=0; j<dg; ++j){
        int c = elist[rs + j];
        const float4* xcp = (const float4*)(xc + (size_t)c*DD + ch*16);
        #pragma unroll
        for (int f4=0; f4<4; ++f4){
          float4 v = xcp[f4];
          s[f4*4+0]+=v.x; s[f4*4+1]+=v.y; s[f4*4+2]+=v.z; s[f4*4+3]+=v.w;
        }
      }
    }
    union { short sh[16]; bfrag v[2]; } u;
    #pragma unroll
    for (int z=0; z<16; ++z) u.sh[z] = bf16c(s[z]);
    *(bfrag*)&As[row][ch*16 + 0] = u.v[0];
    *(bfrag*)&As[row][ch*16 + 8] = u.v[1];
    const float4* xpp = (const float4*)(xp + (size_t)(ok?gr:0)*DD + ch*16);
    union { short sh[16]; bfrag v[2]; } u2;
    #pragma unroll
    for (int f4=0; f4<4; ++f4)
      cvt4(ok ? xpp[f4] : make_float4(0.f,0.f,0.f,0.f), &u2.sh[f4*4]);
    *(bfrag*)&As[row][64 + ch*16 + 0] = u2.v[0];
    *(bfrag*)&As[row][64 + ch*16 + 8] = u2.v[1];
  }
  const int lane = t & 63, w = t >> 6;
  const int lr = lane & 15, lk = lane >> 4;
  f32x4 acc[16];
  #pragma unroll
  for (int i=0;i<16;i++) acc[i] = (f32x4){0.f,0.f,0.f,0.f};

  for (int ks=0; ks<4; ++ks){
    __syncthreads();
    {
      const bfrag* src = (const bfrag*)(Wu_bf + t*128 + ks*32);
      #pragma unroll
      for (int cc=0;cc<4;cc++) *(bfrag*)&Bs[t][cc*8] = src[cc];
    }
    __syncthreads();
    bfrag a = *(const bfrag*)&As[w*16 + lr][ks*32 + lk*8];
    #pragma unroll
    for (int nt=0; nt<16; ++nt){
      bfrag b = *(const bfrag*)&Bs[nt*16 + lr][lk*8];
      acc[nt] = __builtin_amdgcn_mfma_f32_16x16x32_bf16(a, b, acc[nt], 0, 0, 0);
    }
  }
  #pragma unroll
  for (int r=0; r<4; ++r){
    int idx = base + w*16 + lk*4 + r;
    if (idx >= nv) continue;
    int m = vlist[idx];
    #pragma unroll
    for (int q=0; q<4; ++q){
      int d = lr + 16*q;
      float gi = acc[q][r]    + bihu[d]       + bhhu[d];
      float gf = acc[4+q][r]  + bihu[64 + d]  + bhhu[64 + d];
      float gn = acc[8+q][r]  + bihu[128 + d] + bhhu[128 + d];
      float go = acc[12+q][r] + bihu[192 + d] + bhhu[192 + d];
      float cold = xph[(size_t)m*DD + d];
      float cn = sigmf(gf)*cold + sigmf(gi)*tanhfast(gn);
      float hn = sigmf(go)*tanhfast(cn);
      xp[(size_t)m*DD + d]  = hn;
      xph[(size_t)m*DD + d] = cn;
    }
  }
}

// ---------------- Gram: G[v][u] = bf16(emb[v])·bf16(emb[u]) + cbias[u] ----------------
__launch_bounds__(256)
__global__ void k_gram(const short* __restrict__ emb_bf, const float* __restrict__ cbias,
                       float* __restrict__ G, int V){
  __shared__ __align__(16) short As[64][72];
  __shared__ __align__(16) short Bs[400][40];
  const int t = threadIdx.x;
  const int base = blockIdx.x*64;
  {
    int row = t >> 2, ch = t & 3;
    int gr = base + row;
    union { short sh[16]; bfrag v[2]; } u;
    if (gr < V){
      const bfrag* src = (const bfrag*)(emb_bf + gr*64 + ch*16);
      u.v[0] = src[0]; u.v[1] = src[1];
    } else {
      #pragma unroll
      for (int z=0; z<16; ++z) u.sh[z] = 0;
    }
    *(bfrag*)&As[row][ch*16 + 0] = u.v[0];
    *(bfrag*)&As[row][ch*16 + 8] = u.v[1];
  }
  const int lane = t & 63, w = t >> 6;
  const int lr = lane & 15, lk = lane >> 4;
  f32x4 acc[25];
  #pragma unroll
  for (int i=0;i<25;i++) acc[i] = (f32x4){0.f,0.f,0.f,0.f};
  for (int ks=0; ks<2; ++ks){
    __syncthreads();
    for (int nn = t; nn < 400; nn += 256){
      const bfrag* src = (const bfrag*)(emb_bf + nn*64 + ks*32);
      #pragma unroll
      for (int cc=0;cc<4;cc++) *(bfrag*)&Bs[nn][cc*8] = src[cc];
    }
    __syncthreads();
    bfrag a = *(const bfrag*)&As[w*16 + lr][ks*32 + lk*8];
    #pragma unroll
    for (int nt=0; nt<25; ++nt){
      bfrag b = *(const bfrag*)&Bs[nt*16 + lr][lk*8];
      acc[nt] = __builtin_amdgcn_mfma_f32_16x16x32_bf16(a, b, acc[nt], 0, 0, 0);
    }
  }
  #pragma unroll
  for (int r=0; r<4; ++r){
    int m = base + w*16 + lk*4 + r;
    if (m >= V) continue;
    #pragma unroll
    for (int nt=0; nt<25; ++nt){
      int v = nt*16 + lr;
      G[(size_t)m*V + v] = acc[nt][r] + cbias[v];
    }
  }
}

// ---------------- fixed-point logits: copy G[y[p]] row ----------------
__global__ void k_fixed_copy(const float* __restrict__ G, const int* __restrict__ flist,
                             const int* __restrict__ y, const int* __restrict__ nfp,
                             float* __restrict__ out, int V){
  const int nq = V >> 2;                 // float4 per row (100)
  const int nf = nfp[0];
  const int total = nf * nq;
  for (int i = blockIdx.x*256 + threadIdx.x; i < total; i += gridDim.x*256){
    int p = flist[i / nq];
    int c4 = i % nq;
    float4 g = ((const float4*)(G + (size_t)y[p]*V))[c4];
    ((float4*)(out + (size_t)p*V))[c4] = g;
  }
}

// ---------------- variable-point logits: MFMA, K=64, N=400; LDS-transposed stores ----------------
#define ST 212
__launch_bounds__(256)
__global__ void k_logits_mfma(const float* __restrict__ xp, const short* __restrict__ emb_bf,
                              const float* __restrict__ cbias, const int* __restrict__ vlist,
                              const int* __restrict__ nvp,
                              float* __restrict__ out, int NP, int V){
  const int nv = nvp[0];
  const int base = blockIdx.x*64;
  if (base >= nv) return;
  __shared__ __align__(16) char smem[64*ST*4];   // 54272 B; staging (41216 B) overlaps
  short (*As)[72] = (short (*)[72])smem;
  short (*Bs)[40] = (short (*)[40])(smem + 64*72*2);
  float (*T)[ST]  = (float (*)[ST])smem;
  const int t = threadIdx.x;
  {
    int row = t >> 2, ch = t & 3;
    int idx = base + row;
    int gr = (idx < nv) ? vlist[idx] : -1;
    const float* src = (gr >= 0) ? xp + (size_t)gr*DD + ch*16 : nullptr;
    union { short s[16]; bfrag v[2]; } u;
    #pragma unroll
    for (int f4=0; f4<4; ++f4){
      float4 val = src ? ((const float4*)src)[f4] : make_float4(0.f,0.f,0.f,0.f);
      cvt4(val, &u.s[f4*4]);
    }
    *(bfrag*)&As[row][ch*16 + 0] = u.v[0];
    *(bfrag*)&As[row][ch*16 + 8] = u.v[1];
  }
  const int lane = t & 63, w = t >> 6;
  const int lr = lane & 15, lk = lane >> 4;
  f32x4 acc[25];
  #pragma unroll
  for (int i=0;i<25;i++) acc[i] = (f32x4){0.f,0.f,0.f,0.f};
  for (int ks=0; ks<2; ++ks){
    __syncthreads();
    for (int nn = t; nn < 400; nn += 256){
      const bfrag* src = (const bfrag*)(emb_bf + nn*64 + ks*32);
      #pragma unroll
      for (int cc=0;cc<4;cc++) *(bfrag*)&Bs[nn][cc*8] = src[cc];
    }
    __syncthreads();
    bfrag a = *(const bfrag*)&As[w*16 + lr][ks*32 + lk*8];
    #pragma unroll
    for (int nt=0; nt<25; ++nt){
      bfrag b = *(const bfrag*)&Bs[nt*16 + lr][lk*8];
      acc[nt] = __builtin_amdgcn_mfma_f32_16x16x32_bf16(a, b, acc[nt], 0, 0, 0);
    }
  }
  // epilogue: transpose in LDS -> float4 stores. chunk0: nt 0..12 (208 cols), chunk1: nt 13..24 (192)
  const int row_t = t >> 2, q = t & 3;
  const int vrow = base + row_t;
  const int m = (vrow < nv) ? vlist[vrow] : -1;
  #pragma unroll
  for (int chunk=0; chunk<2; ++chunk){
    const int nt0 = chunk ? 13 : 0;
    const int nt1 = chunk ? 25 : 13;
    const int cb  = nt0*16;
    __syncthreads();
    #pragma unroll
    for (int nt=nt0; nt<nt1; ++nt){
      #pragma unroll
      for (int r=0; r<4; ++r)
        T[w*16 + lk*4 + r][nt*16 + lr - cb] = acc[nt][r];
    }
    __syncthreads();
    const int nk = chunk ? 12 : 13;
    if (m >= 0){
      for (int k=0; k<nk; ++k){
        int c4 = q + 4*k;
        int col = cb + c4*4;
        float4 val = *(float4*)&T[row_t][c4*4];
        float4 cbv = *(const float4*)(cbias + col);
        val.x += cbv.x; val.y += cbv.y; val.z += cbv.z; val.w += cbv.w;
        *(float4*)(out + (size_t)m*V + col) = val;
      }
    }
  }
}

extern "C" void kernel_launch(void* const* d_in, const int* in_sizes, int n_in,
                              void* d_out, int out_size, void* d_ws, size_t ws_size,
                              hipStream_t stream){
  const float* emb   = (const float*)d_in[0];
  const float* cbias = (const float*)d_in[1];
  const float* Wci   = (const float*)d_in[2];
  const float* bci   = (const float*)d_in[3];
  const float* Wihc  = (const float*)d_in[4];
  const float* Whhc  = (const float*)d_in[5];
  const float* bihc  = (const float*)d_in[6];
  const float* bhhc  = (const float*)d_in[7];
  const float* Wihu  = (const float*)d_in[8];
  const float* Whhu  = (const float*)d_in[9];
  const float* bihu  = (const float*)d_in[10];
  const float* bhhu  = (const float*)d_in[11];
  const float* xpr   = (const float*)d_in[12];
  const int* y    = (const int*)d_in[13];
  const int* pt   = (const int*)d_in[14];
  const int* ct   = (const int*)d_in[15];
  const int* p2c  = (const int*)d_in[16];
  const int NP = in_sizes[13];
  const int NC = in_sizes[15];
  const int V  = in_sizes[1];
  const int NE = NC*4;

  char* w = (char*)d_ws;
  auto alloc = [&](size_t bytes)->char*{ char* p = w; w += (bytes + 255) & ~255ull; return p; };
  float* xp   = (float*)alloc((size_t)NP*DD*4);
  float* xph  = (float*)alloc((size_t)NP*DD*4);
  float* xc   = (float*)alloc((size_t)NC*DD*4);
  float* xch  = (float*)alloc((size_t)NC*DD*4);
  int*   tlist= (int*)alloc((size_t)4*NC*4);
  int*   cnt  = (int*)alloc(256);
  int*   cnt2 = (int*)alloc(256);
  short* Wc_bf = (short*)alloc((size_t)4*256*320*2);
  short* Wu_bf = (short*)alloc((size_t)256*128*2);
  short* emb_bf= (short*)alloc((size_t)400*64*2);
  int*   deg     = (int*)alloc((size_t)NP*4);
  int*   cursor  = (int*)alloc((size_t)NP*4);
  int*   rowstart= (int*)alloc((size_t)NP*4);
  int*   elist   = (int*)alloc((size_t)NE*4);
  int*   bsum    = (int*)alloc(4096);
  int*   vlist   = (int*)alloc((size_t)NP*4);
  int*   flist   = (int*)alloc((size_t)NP*4);
  float* G       = (float*)alloc((size_t)V*V*4);

  const int NB = (NP + 255)/256;   // 782 <= 1024

  hipMemsetAsync(cnt, 0, 16, stream);
  hipMemsetAsync(cnt2, 0, 16, stream);
  hipMemsetAsync(deg, 0, (size_t)NP*8, stream);   // deg + cursor (adjacent allocs)
  k_cvt<<<(4*256*320 + 256*128 + 400*64 + 255)/256, 256, 0, stream>>>(
      Wihc, Whhc, Wihu, Whhu, emb, Wc_bf, Wu_bf, emb_bf);
  k_init_points<<<(NP*16+255)/256, 256, 0, stream>>>(emb, xpr, y, pt, xp, xph, NP);
  k_init_clauses<<<(NC*16+255)/256, 256, 0, stream>>>(Wci, bci, xc, xch, NC);
  k_classify<<<(NC+255)/256, 256, 0, stream>>>(ct, tlist, cnt, NC);
  k_compact<<<(NP+255)/256, 256, 0, stream>>>(pt, vlist, flist, cnt2, NP);
  // CSR build (graph constant across iterations)
  k_deg<<<(NE+255)/256, 256, 0, stream>>>(p2c, deg, NE);
  k_blocksum<<<NB, 256, 0, stream>>>(deg, bsum, NP);
  k_scanblk<<<1, 1024, 0, stream>>>(bsum, NB);
  k_scanchunk<<<NB, 256, 0, stream>>>(deg, bsum, rowstart, NP);
  k_fill<<<(NE+255)/256, 256, 0, stream>>>(p2c, rowstart, cursor, elist, NE);
  k_gram<<<(V+63)/64, 256, 0, stream>>>(emb_bf, cbias, G, V);

  const int ctiles = (NC+63)/64;
  const int num_iters = 2;  // fixed by the problem instance
  for (int it=0; it<num_iters; ++it){
    k_clause_mfma<<<dim3(ctiles,4), 256, 0, stream>>>(Wc_bf, bihc, bhhc, xp, xc, xch,
                                                      p2c, tlist, cnt, NC);
    k_point_mfma<<<(NP+63)/64, 256, 0, stream>>>(Wu_bf, bihu, bhhu, xc,
                                                 rowstart, deg, elist, vlist, cnt2,
                                                 xp, xph, NP);
  }
  k_fixed_copy<<<2048, 256, 0, stream>>>(G, flist, y, cnt2+1, (float*)d_out, V);
  k_logits_mfma<<<(NP+63)/64, 256, 0, stream>>>(xp, emb_bf, cbias, vlist, cnt2,
                                                (float*)d_out, NP, V);
}

// Round 6
// 498.193 us; speedup vs baseline: 3.0611x; 1.0234x over previous
//
#include <hip/hip_runtime.h>
#include <hip/hip_bf16.h>

#define DD 64
#define GG 256

typedef __attribute__((ext_vector_type(8))) __bf16 bfrag;   // 8 bf16 = 4 VGPRs
typedef __attribute__((ext_vector_type(4))) float f32x4;

__device__ __forceinline__ float sigmf(float x){ return 1.f/(1.f+__expf(-x)); }
__device__ __forceinline__ float tanhfast(float x){ return 1.f - 2.f/(__expf(2.f*x)+1.f); }
__device__ __forceinline__ short bf16c(float f){
  __hip_bfloat16 h = __float2bfloat16(f);
  return *reinterpret_cast<short*>(&h);
}

// ================= fused setup: weight permute + inits + classify + compact + deg ==========
// Weight layouts (fragment-order, so MFMA B-operand = one 16B load):
//   Wc_lay[tp][ks10][nt16][lr16][lk4][e8], Wu_lay[ks4][nt16][lr][lk][e], E_lay[ks2][nt25][lr][lk][e]
__global__ void k_setup(
    const float* __restrict__ Wihc, const float* __restrict__ Whhc,
    const float* __restrict__ Wihu, const float* __restrict__ Whhu,
    const float* __restrict__ emb, const float* __restrict__ Wci,
    const float* __restrict__ bci, const float* __restrict__ xpr,
    const int* __restrict__ y, const int* __restrict__ pt,
    const int* __restrict__ ct, const int* __restrict__ p2c,
    short* __restrict__ Wc_lay, short* __restrict__ Wu_lay,
    short* __restrict__ E_lay, short* __restrict__ emb_bf,
    short* __restrict__ xp_bf, float* __restrict__ xph,
    short* __restrict__ xc_bf, float* __restrict__ xch,
    int* __restrict__ tlist, int* __restrict__ cnt,
    int* __restrict__ vlist, int* __restrict__ flist, int* __restrict__ cnt2,
    int* __restrict__ deg, int NP, int NC)
{
  int b = blockIdx.x;
  const int t = threadIdx.x;
  if (b < 1280){                       // Wc_lay: 4*10*16*16*4*8 = 327680
    int idx = b*256 + t;
    int tp = idx / 81920, r = idx % 81920;
    int ks = r / 8192;  int r2 = r % 8192;
    int nt = r2 / 512;  int r3 = r2 % 512;
    int lr = r3 / 32;   int r4 = r3 % 32;
    int lk = r4 / 8,    e  = r4 % 8;
    int g = nt*16 + lr, k = ks*32 + lk*8 + e;
    float v = (k < 256) ? Wihc[((size_t)tp*256+g)*256 + k]
                        : Whhc[((size_t)tp*256+g)*64 + (k-256)];
    Wc_lay[idx] = bf16c(v);
    return;
  }
  b -= 1280;
  if (b < 128){                        // Wu_lay: 4*16*16*4*8 = 32768
    int idx = b*256 + t;
    int ks = idx / 8192; int r2 = idx % 8192;
    int nt = r2 / 512;   int r3 = r2 % 512;
    int lr = r3 / 32;    int r4 = r3 % 32;
    int lk = r4 / 8,     e  = r4 % 8;
    int g = nt*16 + lr, k = ks*32 + lk*8 + e;
    float v = (k < 64) ? Wihu[g*64 + k] : Whhu[g*64 + (k-64)];
    Wu_lay[idx] = bf16c(v);
    return;
  }
  b -= 128;
  if (b < 100){                        // E_lay: 2*25*16*4*8 = 25600
    int idx = b*256 + t;
    int ks = idx / 12800; int r = idx % 12800;
    int nt = r / 512;     int r3 = r % 512;
    int lr = r3 / 32;     int r4 = r3 % 32;
    int lk = r4 / 8,      e  = r4 % 8;
    int v = nt*16 + lr, k = ks*32 + lk*8 + e;
    E_lay[idx] = bf16c(emb[v*64 + k]);
    return;
  }
  b -= 100;
  if (b < 100){                        // emb_bf: 400*64
    int e = b*256 + t;
    emb_bf[e] = bf16c(emb[e]);
    return;
  }
  b -= 100;
  int nbP4 = (NP*4 + 255) >> 8;
  if (b < nbP4){                       // init points (bf16 x_p, zero xph)
    int i = b*256 + t;
    if (i < NP*4){
      int p = i >> 2, ch = i & 3;
      const float* src = (pt[p]!=0) ? (emb + (size_t)y[p]*DD + ch*16)
                                    : (xpr + (size_t)p*DD + ch*16);
      short o[16];
      #pragma unroll
      for (int f4=0; f4<4; ++f4){
        float4 v = ((const float4*)src)[f4];
        o[f4*4+0]=bf16c(v.x); o[f4*4+1]=bf16c(v.y); o[f4*4+2]=bf16c(v.z); o[f4*4+3]=bf16c(v.w);
      }
      *(uint4*)(xp_bf + (size_t)p*DD + ch*16)     = *(uint4*)&o[0];
      *(uint4*)(xp_bf + (size_t)p*DD + ch*16 + 8) = *(uint4*)&o[8];
      float4 z = make_float4(0.f,0.f,0.f,0.f);
      #pragma unroll
      for (int f4=0; f4<4; ++f4) ((float4*)(xph + (size_t)p*DD + ch*16))[f4] = z;
    }
    return;
  }
  b -= nbP4;
  int nbC4 = (NC*4 + 255) >> 8;
  if (b < nbC4){                       // init clauses
    int i = b*256 + t;
    if (i < NC*4){
      int c = i >> 2, ch = i & 3;
      short o[16];
      #pragma unroll
      for (int d=0; d<16; ++d) o[d] = bf16c(Wci[ch*16+d] + bci[ch*16+d]);
      *(uint4*)(xc_bf + (size_t)c*DD + ch*16)     = *(uint4*)&o[0];
      *(uint4*)(xc_bf + (size_t)c*DD + ch*16 + 8) = *(uint4*)&o[8];
      float4 z = make_float4(0.f,0.f,0.f,0.f);
      #pragma unroll
      for (int f4=0; f4<4; ++f4) ((float4*)(xch + (size_t)c*DD + ch*16))[f4] = z;
    }
    return;
  }
  b -= nbC4;
  int nbCl = (NC + 255) >> 8;
  if (b < nbCl){                       // classify (wave-aggregated)
    int c = b*256 + t;
    int lane = t & 63;
    int tp = (c < NC) ? ct[c] : -1;
    unsigned long long lt = (lane == 63) ? ~0ull >> 1 : ((1ull << lane) - 1ull);
    #pragma unroll
    for (int ty=0; ty<4; ++ty){
      unsigned long long m = __ballot(tp==ty);
      if (m == 0ull) continue;
      int nw = __popcll(m), rank = __popcll(m & lt);
      int leader = __ffsll((long long)m) - 1;
      int base = 0;
      if (lane == leader) base = atomicAdd(cnt + ty, nw);
      base = __shfl(base, leader);
      if (tp == ty) tlist[ty*NC + base + rank] = c;
    }
    return;
  }
  b -= nbCl;
  int nbCp = (NP + 255) >> 8;
  if (b < nbCp){                       // compact var/fixed
    int p = b*256 + t;
    int lane = t & 63;
    int cls = (p < NP) ? ((pt[p]==0) ? 0 : 1) : -1;
    unsigned long long lt = (lane == 63) ? ~0ull >> 1 : ((1ull << lane) - 1ull);
    #pragma unroll
    for (int ty=0; ty<2; ++ty){
      unsigned long long m = __ballot(cls==ty);
      if (m == 0ull) continue;
      int nw = __popcll(m), rank = __popcll(m & lt);
      int leader = __ffsll((long long)m) - 1;
      int base = 0;
      if (lane == leader) base = atomicAdd(cnt2 + ty, nw);
      base = __shfl(base, leader);
      if (cls == ty) (ty ? flist : vlist)[base + rank] = p;
    }
    return;
  }
  b -= nbCp;
  {                                    // degree count
    int e = b*256 + t;
    if (e < NC*4) atomicAdd(deg + p2c[e], 1);
  }
}

// ---------------- CSR scan + fill ----------------
__global__ void k_blocksum(const int* __restrict__ deg, int* __restrict__ bsum, int NP){
  int i = blockIdx.x*256 + threadIdx.x;
  int v = (i < NP) ? deg[i] : 0;
  #pragma unroll
  for (int off=32; off>0; off>>=1) v += __shfl_down(v, off);
  __shared__ int ws[4];
  if ((threadIdx.x & 63) == 0) ws[threadIdx.x>>6] = v;
  __syncthreads();
  if (threadIdx.x == 0) bsum[blockIdx.x] = ws[0]+ws[1]+ws[2]+ws[3];
}
__global__ void k_scanblk(int* __restrict__ bsum, int NB){   // single block, 1024 thr
  __shared__ int s[1024];
  int tid = threadIdx.x;
  int v = (tid < NB) ? bsum[tid] : 0;
  s[tid] = v; __syncthreads();
  for (int off=1; off<1024; off<<=1){
    int tv = (tid >= off) ? s[tid-off] : 0;
    __syncthreads();
    s[tid] += tv;
    __syncthreads();
  }
  if (tid < NB) bsum[tid] = s[tid] - v;   // exclusive
}
__global__ void k_scanchunk(const int* __restrict__ deg, const int* __restrict__ bsum,
                            int* __restrict__ rowstart, int NP){
  __shared__ int s[256];
  int tid = threadIdx.x, i = blockIdx.x*256 + tid;
  int v = (i < NP) ? deg[i] : 0;
  s[tid] = v; __syncthreads();
  for (int off=1; off<256; off<<=1){
    int tv = (tid >= off) ? s[tid-off] : 0;
    __syncthreads();
    s[tid] += tv;
    __syncthreads();
  }
  if (i < NP) rowstart[i] = bsum[blockIdx.x] + s[tid] - v;
}
__global__ void k_fill(const int* __restrict__ p2c, const int* __restrict__ rowstart,
                       int* __restrict__ cursor, int* __restrict__ elist, int NE){
  int e = blockIdx.x*256 + threadIdx.x;
  if (e >= NE) return;
  int p = p2c[e];
  int pos = atomicAdd(cursor + p, 1);
  elist[rowstart[p] + pos] = e >> 2;   // clause index
}

// ---------------- clause LSTM: barrier-free K-loop, B direct from global ----------------
__launch_bounds__(256)
__global__ void k_clause(const short* __restrict__ Wc_lay,
                         const float* __restrict__ bih, const float* __restrict__ bhh,
                         const short* __restrict__ xp_bf,
                         short* __restrict__ xc_bf, float* __restrict__ xch,
                         const int* __restrict__ p2c, const int* __restrict__ tlist,
                         const int* __restrict__ cnt, int NC){
  __shared__ __align__(16) short As[64][328];
  const int tp = blockIdx.y;
  const int n = cnt[tp];
  const int base = blockIdx.x*64;
  if (base >= n) return;
  const int t = threadIdx.x;
  {
    int row = t >> 2, ch = t & 3;
    int idx = base + row;
    int c = (idx < n) ? tlist[tp*NC + idx] : -1;
    #pragma unroll
    for (int slot=0; slot<5; ++slot){
      uint4 v0 = make_uint4(0,0,0,0), v1 = make_uint4(0,0,0,0);
      const short* src = nullptr;
      if (c >= 0){
        if (slot < 4){
          if (!(tp==3 && slot==3)){          // midpoint zeros 4th slot
            int p = p2c[c*4 + slot];
            src = xp_bf + (size_t)p*DD + ch*16;
          }
        } else src = xc_bf + (size_t)c*DD + ch*16;
      }
      if (src){ v0 = *(const uint4*)src; v1 = *(const uint4*)(src+8); }
      *(uint4*)&As[row][slot*64 + ch*16 + 0] = v0;
      *(uint4*)&As[row][slot*64 + ch*16 + 8] = v1;
    }
  }
  __syncthreads();
  const int lane = t & 63, w = t >> 6;
  const int lr = lane & 15, lk = lane >> 4;
  f32x4 acc[16];
  #pragma unroll
  for (int i=0;i<16;i++) acc[i] = (f32x4){0.f,0.f,0.f,0.f};
  const short* wb = Wc_lay + (size_t)tp*81920 + (lr*4 + lk)*8;
  #pragma unroll
  for (int ks=0; ks<10; ++ks){
    bfrag a = *(const bfrag*)&As[w*16 + lr][ks*32 + lk*8];
    #pragma unroll
    for (int nt=0; nt<16; ++nt){
      bfrag bv = *(const bfrag*)(wb + (ks*16 + nt)*512);
      acc[nt] = __builtin_amdgcn_mfma_f32_16x16x32_bf16(a, bv, acc[nt], 0, 0, 0);
    }
  }
  #pragma unroll
  for (int r=0; r<4; ++r){
    int idx = base + w*16 + lk*4 + r;
    if (idx >= n) continue;
    int c = tlist[tp*NC + idx];
    #pragma unroll
    for (int q=0; q<4; ++q){
      int d = lr + 16*q;
      float gi = acc[q][r]    + bih[tp*GG + d]       + bhh[tp*GG + d];
      float gf = acc[4+q][r]  + bih[tp*GG + 64 + d]  + bhh[tp*GG + 64 + d];
      float gn = acc[8+q][r]  + bih[tp*GG + 128 + d] + bhh[tp*GG + 128 + d];
      float go = acc[12+q][r] + bih[tp*GG + 192 + d] + bhh[tp*GG + 192 + d];
      float cold = xch[(size_t)c*DD + d];
      float cn = sigmf(gf)*cold + sigmf(gi)*tanhfast(gn);
      float hn = sigmf(go)*tanhfast(cn);
      xc_bf[(size_t)c*DD + d] = bf16c(hn);
      xch[(size_t)c*DD + d]   = cn;
    }
  }
}

// ---------------- point LSTM: var points only; CSR gather fused; barrier-free K-loop ----------
__launch_bounds__(256)
__global__ void k_point(const short* __restrict__ Wu_lay,
                        const float* __restrict__ bihu, const float* __restrict__ bhhu,
                        const short* __restrict__ xc_bf,
                        const int* __restrict__ rowstart, const int* __restrict__ deg,
                        const int* __restrict__ elist, const int* __restrict__ vlist,
                        const int* __restrict__ nvp,
                        short* __restrict__ xp_bf, float* __restrict__ xph, int NP){
  const int nv = nvp[0];
  const int base = blockIdx.x*64;
  if (base >= nv) return;
  __shared__ __align__(16) short As[64][136];
  const int t = threadIdx.x;
  {
    int row = t >> 2, ch = t & 3;
    int idx = base + row;
    int gr = (idx < nv) ? vlist[idx] : -1;
    float s[16];
    #pragma unroll
    for (int z=0; z<16; ++z) s[z] = 0.f;
    uint4 xv0 = make_uint4(0,0,0,0), xv1 = make_uint4(0,0,0,0);
    if (gr >= 0){
      int rs = rowstart[gr], dg = deg[gr];
      for (int j=0; j<dg; ++j){
        int c = elist[rs + j];
        const uint4* xcp = (const uint4*)(xc_bf + (size_t)c*DD + ch*16);
        uint4 u0 = xcp[0], u1 = xcp[1];
        uint ua[8] = {u0.x,u0.y,u0.z,u0.w,u1.x,u1.y,u1.z,u1.w};
        #pragma unroll
        for (int i2=0;i2<8;i2++){
          s[i2*2]   += __uint_as_float(ua[i2] << 16);
          s[i2*2+1] += __uint_as_float(ua[i2] & 0xffff0000u);
        }
      }
      const uint4* xpp = (const uint4*)(xp_bf + (size_t)gr*DD + ch*16);
      xv0 = xpp[0]; xv1 = xpp[1];
    }
    short os[16];
    #pragma unroll
    for (int z=0; z<16; ++z) os[z] = bf16c(s[z]);
    *(uint4*)&As[row][ch*16 + 0] = *(uint4*)&os[0];
    *(uint4*)&As[row][ch*16 + 8] = *(uint4*)&os[8];
    *(uint4*)&As[row][64 + ch*16 + 0] = xv0;
    *(uint4*)&As[row][64 + ch*16 + 8] = xv1;
  }
  __syncthreads();
  const int lane = t & 63, w = t >> 6;
  const int lr = lane & 15, lk = lane >> 4;
  f32x4 acc[16];
  #pragma unroll
  for (int i=0;i<16;i++) acc[i] = (f32x4){0.f,0.f,0.f,0.f};
  const short* wb = Wu_lay + (lr*4 + lk)*8;
  #pragma unroll
  for (int ks=0; ks<4; ++ks){
    bfrag a = *(const bfrag*)&As[w*16 + lr][ks*32 + lk*8];
    #pragma unroll
    for (int nt=0; nt<16; ++nt){
      bfrag bv = *(const bfrag*)(wb + (ks*16 + nt)*512);
      acc[nt] = __builtin_amdgcn_mfma_f32_16x16x32_bf16(a, bv, acc[nt], 0, 0, 0);
    }
  }
  #pragma unroll
  for (int r=0; r<4; ++r){
    int idx = base + w*16 + lk*4 + r;
    if (idx >= nv) continue;
    int m = vlist[idx];
    #pragma unroll
    for (int q=0; q<4; ++q){
      int d = lr + 16*q;
      float gi = acc[q][r]    + bihu[d]       + bhhu[d];
      float gf = acc[4+q][r]  + bihu[64 + d]  + bhhu[64 + d];
      float gn = acc[8+q][r]  + bihu[128 + d] + bhhu[128 + d];
      float go = acc[12+q][r] + bihu[192 + d] + bhhu[192 + d];
      float cold = xph[(size_t)m*DD + d];
      float cn = sigmf(gf)*cold + sigmf(gi)*tanhfast(gn);
      float hn = sigmf(go)*tanhfast(cn);
      xp_bf[(size_t)m*DD + d] = bf16c(hn);
      xph[(size_t)m*DD + d]   = cn;
    }
  }
}

// ---------------- Gram: G[v][u] = bf16(emb[v])·bf16(emb[u]) + cbias[u] ----------------
__launch_bounds__(256)
__global__ void k_gram(const short* __restrict__ emb_bf, const short* __restrict__ E_lay,
                       const float* __restrict__ cbias, float* __restrict__ G, int V){
  __shared__ __align__(16) short As[64][72];
  const int t = threadIdx.x;
  const int base = blockIdx.x*64;
  {
    int row = t >> 2, ch = t & 3;
    int gr = base + row;
    uint4 v0 = make_uint4(0,0,0,0), v1 = make_uint4(0,0,0,0);
    if (gr < V){
      const uint4* src = (const uint4*)(emb_bf + gr*64 + ch*16);
      v0 = src[0]; v1 = src[1];
    }
    *(uint4*)&As[row][ch*16 + 0] = v0;
    *(uint4*)&As[row][ch*16 + 8] = v1;
  }
  __syncthreads();
  const int lane = t & 63, w = t >> 6;
  const int lr = lane & 15, lk = lane >> 4;
  f32x4 acc[25];
  #pragma unroll
  for (int i=0;i<25;i++) acc[i] = (f32x4){0.f,0.f,0.f,0.f};
  const short* wb = E_lay + (lr*4 + lk)*8;
  #pragma unroll
  for (int ks=0; ks<2; ++ks){
    bfrag a = *(const bfrag*)&As[w*16 + lr][ks*32 + lk*8];
    #pragma unroll
    for (int nt=0; nt<25; ++nt){
      bfrag bv = *(const bfrag*)(wb + (ks*25 + nt)*512);
      acc[nt] = __builtin_amdgcn_mfma_f32_16x16x32_bf16(a, bv, acc[nt], 0, 0, 0);
    }
  }
  #pragma unroll
  for (int r=0; r<4; ++r){
    int m = base + w*16 + lk*4 + r;
    if (m >= V) continue;
    #pragma unroll
    for (int nt=0; nt<25; ++nt){
      int v = nt*16 + lr;
      G[(size_t)m*V + v] = acc[nt][r] + cbias[v];
    }
  }
}

// ---------------- fixed-point logits: copy G[y[p]] row ----------------
__global__ void k_fixed_copy(const float* __restrict__ G, const int* __restrict__ flist,
                             const int* __restrict__ y, const int* __restrict__ nfp,
                             float* __restrict__ out, int V){
  const int nq = V >> 2;                 // float4 per row (100)
  const int nf = nfp[0];
  const int total = nf * nq;
  for (int i = blockIdx.x*256 + threadIdx.x; i < total; i += gridDim.x*256){
    int p = flist[i / nq];
    int c4 = i % nq;
    float4 g = ((const float4*)(G + (size_t)y[p]*V))[c4];
    ((float4*)(out + (size_t)p*V))[c4] = g;
  }
}

// ---------------- variable-point logits: barrier-free MFMA + LDS-transposed float4 stores ----
#define ST 212
__launch_bounds__(256)
__global__ void k_logits(const short* __restrict__ xp_bf, const short* __restrict__ E_lay,
                         const float* __restrict__ cbias, const int* __restrict__ vlist,
                         const int* __restrict__ nvp,
                         float* __restrict__ out, int NP, int V){
  const int nv = nvp[0];
  const int base = blockIdx.x*64;
  if (base >= nv) return;
  __shared__ __align__(16) char smem[64*ST*4];
  short (*As)[72] = (short (*)[72])smem;
  float (*T)[ST]  = (float (*)[ST])smem;   // overlays As after MFMA phase
  const int t = threadIdx.x;
  {
    int row = t >> 2, ch = t & 3;
    int idx = base + row;
    int gr = (idx < nv) ? vlist[idx] : -1;
    uint4 v0 = make_uint4(0,0,0,0), v1 = make_uint4(0,0,0,0);
    if (gr >= 0){
      const uint4* src = (const uint4*)(xp_bf + (size_t)gr*DD + ch*16);
      v0 = src[0]; v1 = src[1];
    }
    *(uint4*)&As[row][ch*16 + 0] = v0;
    *(uint4*)&As[row][ch*16 + 8] = v1;
  }
  __syncthreads();
  const int lane = t & 63, w = t >> 6;
  const int lr = lane & 15, lk = lane >> 4;
  f32x4 acc[25];
  #pragma unroll
  for (int i=0;i<25;i++) acc[i] = (f32x4){0.f,0.f,0.f,0.f};
  const short* wb = E_lay + (lr*4 + lk)*8;
  #pragma unroll
  for (int ks=0; ks<2; ++ks){
    bfrag a = *(const bfrag*)&As[w*16 + lr][ks*32 + lk*8];
    #pragma unroll
    for (int nt=0; nt<25; ++nt){
      bfrag bv = *(const bfrag*)(wb + (ks*25 + nt)*512);
      acc[nt] = __builtin_amdgcn_mfma_f32_16x16x32_bf16(a, bv, acc[nt], 0, 0, 0);
    }
  }
  const int row_t = t >> 2, q = t & 3;
  const int vrow = base + row_t;
  const int m = (vrow < nv) ? vlist[vrow] : -1;
  #pragma unroll
  for (int chunk=0; chunk<2; ++chunk){
    const int nt0 = chunk ? 13 : 0;
    const int nt1 = chunk ? 25 : 13;
    const int cb  = nt0*16;
    __syncthreads();
    #pragma unroll
    for (int nt=nt0; nt<nt1; ++nt){
      #pragma unroll
      for (int r=0; r<4; ++r)
        T[w*16 + lk*4 + r][nt*16 + lr - cb] = acc[nt][r];
    }
    __syncthreads();
    const int nk = chunk ? 12 : 13;
    if (m >= 0){
      for (int k=0; k<nk; ++k){
        int c4 = q + 4*k;
        int col = cb + c4*4;
        float4 val = *(float4*)&T[row_t][c4*4];
        float4 cbv = *(const float4*)(cbias + col);
        val.x += cbv.x; val.y += cbv.y; val.z += cbv.z; val.w += cbv.w;
        *(float4*)(out + (size_t)m*V + col) = val;
      }
    }
  }
}

extern "C" void kernel_launch(void* const* d_in, const int* in_sizes, int n_in,
                              void* d_out, int out_size, void* d_ws, size_t ws_size,
                              hipStream_t stream){
  const float* emb   = (const float*)d_in[0];
  const float* cbias = (const float*)d_in[1];
  const float* Wci   = (const float*)d_in[2];
  const float* bci   = (const float*)d_in[3];
  const float* Wihc  = (const float*)d_in[4];
  const float* Whhc  = (const float*)d_in[5];
  const float* bihc  = (const float*)d_in[6];
  const float* bhhc  = (const float*)d_in[7];
  const float* Wihu  = (const float*)d_in[8];
  const float* Whhu  = (const float*)d_in[9];
  const float* bihu  = (const float*)d_in[10];
  const float* bhhu  = (const float*)d_in[11];
  const float* xpr   = (const float*)d_in[12];
  const int* y    = (const int*)d_in[13];
  const int* pt   = (const int*)d_in[14];
  const int* ct   = (const int*)d_in[15];
  const int* p2c  = (const int*)d_in[16];
  const int NP = in_sizes[13];
  const int NC = in_sizes[15];
  const int V  = in_sizes[1];
  const int NE = NC*4;

  char* w = (char*)d_ws;
  auto alloc = [&](size_t bytes)->char*{ char* p = w; w += (bytes + 255) & ~255ull; return p; };
  short* xp_bf = (short*)alloc((size_t)NP*DD*2);
  float* xph   = (float*)alloc((size_t)NP*DD*4);
  short* xc_bf = (short*)alloc((size_t)NC*DD*2);
  float* xch   = (float*)alloc((size_t)NC*DD*4);
  int*   tlist = (int*)alloc((size_t)4*NC*4);
  int*   ctr   = (int*)alloc(256);            // [0..3]=cnt, [16..17]=cnt2
  short* Wc_lay= (short*)alloc((size_t)327680*2);
  short* Wu_lay= (short*)alloc((size_t)32768*2);
  short* E_lay = (short*)alloc((size_t)25600*2);
  short* emb_bf= (short*)alloc((size_t)25600*2);
  int*   deg     = (int*)alloc((size_t)NP*4);
  int*   cursor  = (int*)alloc((size_t)NP*4);  // adjacent to deg (NP*4 is 256B-aligned)
  int*   rowstart= (int*)alloc((size_t)NP*4);
  int*   elist   = (int*)alloc((size_t)NE*4);
  int*   bsum    = (int*)alloc(4096);
  int*   vlist   = (int*)alloc((size_t)NP*4);
  int*   flist   = (int*)alloc((size_t)NP*4);
  float* G       = (float*)alloc((size_t)V*V*4);
  int* cnt  = ctr;
  int* cnt2 = ctr + 16;

  const int NB   = (NP + 255)/256;
  const int nbP4 = (NP*4 + 255)/256;
  const int nbC4 = (NC*4 + 255)/256;
  const int nbCl = (NC + 255)/256;
  const int nbCp = NB;
  const int nbE  = (NE + 255)/256;
  const int g_setup = 1280 + 128 + 100 + 100 + nbP4 + nbC4 + nbCl + nbCp + nbE;

  hipMemsetAsync(ctr, 0, 256, stream);
  hipMemsetAsync(deg, 0, (size_t)NP*8, stream);   // deg + cursor
  k_setup<<<g_setup, 256, 0, stream>>>(Wihc, Whhc, Wihu, Whhu, emb, Wci, bci, xpr,
                                       y, pt, ct, p2c,
                                       Wc_lay, Wu_lay, E_lay, emb_bf,
                                       xp_bf, xph, xc_bf, xch,
                                       tlist, cnt, vlist, flist, cnt2, deg, NP, NC);
  k_blocksum<<<NB, 256, 0, stream>>>(deg, bsum, NP);
  k_scanblk<<<1, 1024, 0, stream>>>(bsum, NB);
  k_scanchunk<<<NB, 256, 0, stream>>>(deg, bsum, rowstart, NP);
  k_fill<<<nbE, 256, 0, stream>>>(p2c, rowstart, cursor, elist, NE);
  k_gram<<<(V+63)/64, 256, 0, stream>>>(emb_bf, E_lay, cbias, G, V);

  const int ctiles = (NC+63)/64;
  const int num_iters = 2;  // fixed by the problem instance
  for (int it=0; it<num_iters; ++it){
    k_clause<<<dim3(ctiles,4), 256, 0, stream>>>(Wc_lay, bihc, bhhc, xp_bf, xc_bf, xch,
                                                 p2c, tlist, cnt, NC);
    k_point<<<(NP+63)/64, 256, 0, stream>>>(Wu_lay, bihu, bhhu, xc_bf,
                                            rowstart, deg, elist, vlist, cnt2,
                                            xp_bf, xph, NP);
  }
  k_fixed_copy<<<2048, 256, 0, stream>>>(G, flist, y, cnt2+1, (float*)d_out, V);
  k_logits<<<(NP+63)/64, 256, 0, stream>>>(xp_bf, E_lay, cbias, vlist, cnt2,
                                           (float*)d_out, NP, V);
}

// Round 7
// 445.087 us; speedup vs baseline: 3.4264x; 1.1193x over previous
//
#include <hip/hip_runtime.h>
#include <hip/hip_bf16.h>

#define DD 64
#define GG 256

typedef __attribute__((ext_vector_type(8))) __bf16 bfrag;   // 8 bf16 = 4 VGPRs
typedef __attribute__((ext_vector_type(4))) float f32x4;

__device__ __forceinline__ float sigmf(float x){ return 1.f/(1.f+__expf(-x)); }
__device__ __forceinline__ float tanhfast(float x){ return 1.f - 2.f/(__expf(2.f*x)+1.f); }
__device__ __forceinline__ short bf16c(float f){
  __hip_bfloat16 h = __float2bfloat16(f);
  return *reinterpret_cast<short*>(&h);
}

// ================= fused setup: weight permute + inits + classify + compact + deg ==========
// Weight layouts (fragment-order, MFMA B-operand = one 16B load):
//   Wc_lay[tp][ks10][nt16][lr16][lk4][e8], Wu_lay[ks4][nt16][lr][lk][e], E_lay[ks2][nt25][lr][lk][e]
__global__ void k_setup(
    const float* __restrict__ Wihc, const float* __restrict__ Whhc,
    const float* __restrict__ Wihu, const float* __restrict__ Whhu,
    const float* __restrict__ emb, const float* __restrict__ Wci,
    const float* __restrict__ bci, const float* __restrict__ xpr,
    const int* __restrict__ y, const int* __restrict__ pt,
    const int* __restrict__ ct, const int* __restrict__ p2c,
    short* __restrict__ Wc_lay, short* __restrict__ Wu_lay,
    short* __restrict__ E_lay,
    short* __restrict__ xp_bf, short* __restrict__ xc_bf,
    int* __restrict__ tlist, int* __restrict__ cnt,
    int* __restrict__ vlist, int* __restrict__ cnt2,
    int* __restrict__ deg, int NP, int NC)
{
  int b = blockIdx.x;
  const int t = threadIdx.x;
  if (b < 1280){                       // Wc_lay: 4*10*16*16*4*8 = 327680
    int idx = b*256 + t;
    int tp = idx / 81920, r = idx % 81920;
    int ks = r / 8192;  int r2 = r % 8192;
    int nt = r2 / 512;  int r3 = r2 % 512;
    int lr = r3 / 32;   int r4 = r3 % 32;
    int lk = r4 / 8,    e  = r4 % 8;
    int g = nt*16 + lr, k = ks*32 + lk*8 + e;
    float v = (k < 256) ? Wihc[((size_t)tp*256+g)*256 + k]
                        : Whhc[((size_t)tp*256+g)*64 + (k-256)];
    Wc_lay[idx] = bf16c(v);
    return;
  }
  b -= 1280;
  if (b < 128){                        // Wu_lay: 4*16*16*4*8 = 32768
    int idx = b*256 + t;
    int ks = idx / 8192; int r2 = idx % 8192;
    int nt = r2 / 512;   int r3 = r2 % 512;
    int lr = r3 / 32;    int r4 = r3 % 32;
    int lk = r4 / 8,     e  = r4 % 8;
    int g = nt*16 + lr, k = ks*32 + lk*8 + e;
    float v = (k < 64) ? Wihu[g*64 + k] : Whhu[g*64 + (k-64)];
    Wu_lay[idx] = bf16c(v);
    return;
  }
  b -= 128;
  if (b < 100){                        // E_lay: 2*25*16*4*8 = 25600
    int idx = b*256 + t;
    int ks = idx / 12800; int r = idx % 12800;
    int nt = r / 512;     int r3 = r % 512;
    int lr = r3 / 32;     int r4 = r3 % 32;
    int lk = r4 / 8,      e  = r4 % 8;
    int v = nt*16 + lr, k = ks*32 + lk*8 + e;
    E_lay[idx] = bf16c(emb[v*64 + k]);
    return;
  }
  b -= 100;
  int nbP4 = (NP*4 + 255) >> 8;
  if (b < nbP4){                       // init points (bf16 x_p only)
    int i = b*256 + t;
    if (i < NP*4){
      int p = i >> 2, ch = i & 3;
      const float* src = (pt[p]!=0) ? (emb + (size_t)y[p]*DD + ch*16)
                                    : (xpr + (size_t)p*DD + ch*16);
      short o[16];
      #pragma unroll
      for (int f4=0; f4<4; ++f4){
        float4 v = ((const float4*)src)[f4];
        o[f4*4+0]=bf16c(v.x); o[f4*4+1]=bf16c(v.y); o[f4*4+2]=bf16c(v.z); o[f4*4+3]=bf16c(v.w);
      }
      *(uint4*)(xp_bf + (size_t)p*DD + ch*16)     = *(uint4*)&o[0];
      *(uint4*)(xp_bf + (size_t)p*DD + ch*16 + 8) = *(uint4*)&o[8];
    }
    return;
  }
  b -= nbP4;
  int nbC4 = (NC*4 + 255) >> 8;
  if (b < nbC4){                       // init clauses (bf16 x_c only)
    int i = b*256 + t;
    if (i < NC*4){
      int c = i >> 2, ch = i & 3;
      short o[16];
      #pragma unroll
      for (int d=0; d<16; ++d) o[d] = bf16c(Wci[ch*16+d] + bci[ch*16+d]);
      *(uint4*)(xc_bf + (size_t)c*DD + ch*16)     = *(uint4*)&o[0];
      *(uint4*)(xc_bf + (size_t)c*DD + ch*16 + 8) = *(uint4*)&o[8];
    }
    return;
  }
  b -= nbC4;
  int nbCl = (NC + 255) >> 8;
  if (b < nbCl){                       // classify (wave-aggregated)
    int c = b*256 + t;
    int lane = t & 63;
    int tp = (c < NC) ? ct[c] : -1;
    unsigned long long lt = (lane == 63) ? ~0ull >> 1 : ((1ull << lane) - 1ull);
    #pragma unroll
    for (int ty=0; ty<4; ++ty){
      unsigned long long m = __ballot(tp==ty);
      if (m == 0ull) continue;
      int nw = __popcll(m), rank = __popcll(m & lt);
      int leader = __ffsll((long long)m) - 1;
      int base = 0;
      if (lane == leader) base = atomicAdd(cnt + ty, nw);
      base = __shfl(base, leader);
      if (tp == ty) tlist[ty*NC + base + rank] = c;
    }
    return;
  }
  b -= nbCl;
  int nbCp = (NP + 255) >> 8;
  if (b < nbCp){                       // compact variable points
    int p = b*256 + t;
    int lane = t & 63;
    bool var = (p < NP) && (pt[p]==0);
    unsigned long long lt = (lane == 63) ? ~0ull >> 1 : ((1ull << lane) - 1ull);
    unsigned long long m = __ballot(var);
    if (m){
      int nw = __popcll(m), rank = __popcll(m & lt);
      int leader = __ffsll((long long)m) - 1;
      int base = 0;
      if (lane == leader) base = atomicAdd(cnt2, nw);
      base = __shfl(base, leader);
      if (var) vlist[base + rank] = p;
    }
    return;
  }
  b -= nbCp;
  {                                    // degree count
    int e = b*256 + t;
    if (e < NC*4) atomicAdd(deg + p2c[e], 1);
  }
}

// ---------------- CSR scan + fill ----------------
__global__ void k_blocksum(const int* __restrict__ deg, int* __restrict__ bsum, int NP){
  int i = blockIdx.x*256 + threadIdx.x;
  int v = (i < NP) ? deg[i] : 0;
  #pragma unroll
  for (int off=32; off>0; off>>=1) v += __shfl_down(v, off);
  __shared__ int ws[4];
  if ((threadIdx.x & 63) == 0) ws[threadIdx.x>>6] = v;
  __syncthreads();
  if (threadIdx.x == 0) bsum[blockIdx.x] = ws[0]+ws[1]+ws[2]+ws[3];
}
__global__ void k_scanblk(int* __restrict__ bsum, int NB){   // single block, 1024 thr
  __shared__ int s[1024];
  int tid = threadIdx.x;
  int v = (tid < NB) ? bsum[tid] : 0;
  s[tid] = v; __syncthreads();
  for (int off=1; off<1024; off<<=1){
    int tv = (tid >= off) ? s[tid-off] : 0;
    __syncthreads();
    s[tid] += tv;
    __syncthreads();
  }
  if (tid < NB) bsum[tid] = s[tid] - v;   // exclusive
}
__global__ void k_scanchunk(const int* __restrict__ deg, const int* __restrict__ bsum,
                            int* __restrict__ rowstart, int NP){
  __shared__ int s[256];
  int tid = threadIdx.x, i = blockIdx.x*256 + tid;
  int v = (i < NP) ? deg[i] : 0;
  s[tid] = v; __syncthreads();
  for (int off=1; off<256; off<<=1){
    int tv = (tid >= off) ? s[tid-off] : 0;
    __syncthreads();
    s[tid] += tv;
    __syncthreads();
  }
  if (i < NP) rowstart[i] = bsum[blockIdx.x] + s[tid] - v;
}
__global__ void k_fill(const int* __restrict__ p2c, const int* __restrict__ rowstart,
                       int* __restrict__ cursor, int* __restrict__ elist, int NE){
  int e = blockIdx.x*256 + threadIdx.x;
  if (e >= NE) return;
  int p = p2c[e];
  int pos = atomicAdd(cursor + p, 1);
  elist[rowstart[p] + pos] = e >> 2;   // clause index
}

// ---------------- clause LSTM: 1D-trimmed grid, barrier-free K-loop ----------------
__launch_bounds__(256)
__global__ void k_clause(const short* __restrict__ Wc_lay,
                         const float* __restrict__ bih, const float* __restrict__ bhh,
                         const short* __restrict__ xp_bf,
                         short* __restrict__ xc_bf, float* __restrict__ xch,
                         const int* __restrict__ p2c, const int* __restrict__ tlist,
                         const int* __restrict__ cnt, int NC, int first){
  __shared__ __align__(16) short As[64][328];
  int tp, n, base;
  {
    const int c0=cnt[0], c1=cnt[1], c2=cnt[2], c3=cnt[3];
    int b = blockIdx.x;
    const int t0=(c0+63)>>6;
    if (b < t0){ tp=0; n=c0; base=b<<6; }
    else { b-=t0; const int t1=(c1+63)>>6;
      if (b < t1){ tp=1; n=c1; base=b<<6; }
      else { b-=t1; const int t2=(c2+63)>>6;
        if (b < t2){ tp=2; n=c2; base=b<<6; }
        else { b-=t2; const int t3=(c3+63)>>6;
          if (b < t3){ tp=3; n=c3; base=b<<6; } else return; } } }
  }
  const int t = threadIdx.x;
  {
    int row = t >> 2, ch = t & 3;
    int idx = base + row;
    int c = (idx < n) ? tlist[tp*NC + idx] : -1;
    #pragma unroll
    for (int slot=0; slot<5; ++slot){
      uint4 v0 = make_uint4(0,0,0,0), v1 = make_uint4(0,0,0,0);
      const short* src = nullptr;
      if (c >= 0){
        if (slot < 4){
          if (!(tp==3 && slot==3)){          // midpoint zeros 4th slot
            int p = p2c[c*4 + slot];
            src = xp_bf + (size_t)p*DD + ch*16;
          }
        } else src = xc_bf + (size_t)c*DD + ch*16;
      }
      if (src){ v0 = *(const uint4*)src; v1 = *(const uint4*)(src+8); }
      *(uint4*)&As[row][slot*64 + ch*16 + 0] = v0;
      *(uint4*)&As[row][slot*64 + ch*16 + 8] = v1;
    }
  }
  __syncthreads();
  const int lane = t & 63, w = t >> 6;
  const int lr = lane & 15, lk = lane >> 4;
  f32x4 acc[16];
  #pragma unroll
  for (int i=0;i<16;i++) acc[i] = (f32x4){0.f,0.f,0.f,0.f};
  const short* wb = Wc_lay + (size_t)tp*81920 + (lr*4 + lk)*8;
  #pragma unroll
  for (int ks=0; ks<10; ++ks){
    bfrag a = *(const bfrag*)&As[w*16 + lr][ks*32 + lk*8];
    #pragma unroll
    for (int nt=0; nt<16; ++nt){
      bfrag bv = *(const bfrag*)(wb + (ks*16 + nt)*512);
      acc[nt] = __builtin_amdgcn_mfma_f32_16x16x32_bf16(a, bv, acc[nt], 0, 0, 0);
    }
  }
  #pragma unroll
  for (int r=0; r<4; ++r){
    int idx = base + w*16 + lk*4 + r;
    if (idx >= n) continue;
    int c = tlist[tp*NC + idx];
    #pragma unroll
    for (int q=0; q<4; ++q){
      int d = lr + 16*q;
      float gi = acc[q][r]    + bih[tp*GG + d]       + bhh[tp*GG + d];
      float gf = acc[4+q][r]  + bih[tp*GG + 64 + d]  + bhh[tp*GG + 64 + d];
      float gn = acc[8+q][r]  + bih[tp*GG + 128 + d] + bhh[tp*GG + 128 + d];
      float go = acc[12+q][r] + bih[tp*GG + 192 + d] + bhh[tp*GG + 192 + d];
      float cold = first ? 0.f : xch[(size_t)c*DD + d];
      float cn = sigmf(gf)*cold + sigmf(gi)*tanhfast(gn);
      float hn = sigmf(go)*tanhfast(cn);
      xc_bf[(size_t)c*DD + d] = bf16c(hn);
      xch[(size_t)c*DD + d]   = cn;
    }
  }
}

// ---------------- point LSTM: var points only; CSR gather fused; barrier-free ----------
__launch_bounds__(256)
__global__ void k_point(const short* __restrict__ Wu_lay,
                        const float* __restrict__ bihu, const float* __restrict__ bhhu,
                        const short* __restrict__ xc_bf,
                        const int* __restrict__ rowstart, const int* __restrict__ deg,
                        const int* __restrict__ elist, const int* __restrict__ vlist,
                        const int* __restrict__ nvp,
                        short* __restrict__ xp_bf, float* __restrict__ xph,
                        int NP, int first){
  const int nv = nvp[0];
  const int base = blockIdx.x*64;
  if (base >= nv) return;
  __shared__ __align__(16) short As[64][136];
  const int t = threadIdx.x;
  {
    int row = t >> 2, ch = t & 3;
    int idx = base + row;
    int gr = (idx < nv) ? vlist[idx] : -1;
    float s[16];
    #pragma unroll
    for (int z=0; z<16; ++z) s[z] = 0.f;
    uint4 xv0 = make_uint4(0,0,0,0), xv1 = make_uint4(0,0,0,0);
    if (gr >= 0){
      int rs = rowstart[gr], dg = deg[gr];
      for (int j=0; j<dg; ++j){
        int c = elist[rs + j];
        const uint4* xcp = (const uint4*)(xc_bf + (size_t)c*DD + ch*16);
        uint4 u0 = xcp[0], u1 = xcp[1];
        uint ua[8] = {u0.x,u0.y,u0.z,u0.w,u1.x,u1.y,u1.z,u1.w};
        #pragma unroll
        for (int i2=0;i2<8;i2++){
          s[i2*2]   += __uint_as_float(ua[i2] << 16);
          s[i2*2+1] += __uint_as_float(ua[i2] & 0xffff0000u);
        }
      }
      const uint4* xpp = (const uint4*)(xp_bf + (size_t)gr*DD + ch*16);
      xv0 = xpp[0]; xv1 = xpp[1];
    }
    short os[16];
    #pragma unroll
    for (int z=0; z<16; ++z) os[z] = bf16c(s[z]);
    *(uint4*)&As[row][ch*16 + 0] = *(uint4*)&os[0];
    *(uint4*)&As[row][ch*16 + 8] = *(uint4*)&os[8];
    *(uint4*)&As[row][64 + ch*16 + 0] = xv0;
    *(uint4*)&As[row][64 + ch*16 + 8] = xv1;
  }
  __syncthreads();
  const int lane = t & 63, w = t >> 6;
  const int lr = lane & 15, lk = lane >> 4;
  f32x4 acc[16];
  #pragma unroll
  for (int i=0;i<16;i++) acc[i] = (f32x4){0.f,0.f,0.f,0.f};
  const short* wb = Wu_lay + (lr*4 + lk)*8;
  #pragma unroll
  for (int ks=0; ks<4; ++ks){
    bfrag a = *(const bfrag*)&As[w*16 + lr][ks*32 + lk*8];
    #pragma unroll
    for (int nt=0; nt<16; ++nt){
      bfrag bv = *(const bfrag*)(wb + (ks*16 + nt)*512);
      acc[nt] = __builtin_amdgcn_mfma_f32_16x16x32_bf16(a, bv, acc[nt], 0, 0, 0);
    }
  }
  #pragma unroll
  for (int r=0; r<4; ++r){
    int idx = base + w*16 + lk*4 + r;
    if (idx >= nv) continue;
    int m = vlist[idx];
    #pragma unroll
    for (int q=0; q<4; ++q){
      int d = lr + 16*q;
      float gi = acc[q][r]    + bihu[d]       + bhhu[d];
      float gf = acc[4+q][r]  + bihu[64 + d]  + bhhu[64 + d];
      float gn = acc[8+q][r]  + bihu[128 + d] + bhhu[128 + d];
      float go = acc[12+q][r] + bihu[192 + d] + bhhu[192 + d];
      float cold = first ? 0.f : xph[(size_t)idx*DD + d];   // xph compacted by vlist pos
      float cn = sigmf(gf)*cold + sigmf(gi)*tanhfast(gn);
      float hn = sigmf(go)*tanhfast(cn);
      xp_bf[(size_t)m*DD + d] = bf16c(hn);
      xph[(size_t)idx*DD + d] = cn;
    }
  }
}

// ---------------- unified logits: all points, dense sequential writes ----------------
#define ST 212
__launch_bounds__(256)
__global__ void k_logits(const short* __restrict__ xp_bf, const short* __restrict__ E_lay,
                         const float* __restrict__ cbias,
                         float* __restrict__ out, int NP, int V){
  const int base = blockIdx.x*64;
  __shared__ __align__(16) char smem[64*ST*4];
  short (*As)[72] = (short (*)[72])smem;
  float (*T)[ST]  = (float (*)[ST])smem;   // overlays As after MFMA phase
  const int t = threadIdx.x;
  {
    int row = t >> 2, ch = t & 3;
    int gr = base + row;
    uint4 v0 = make_uint4(0,0,0,0), v1 = make_uint4(0,0,0,0);
    if (gr < NP){
      const uint4* src = (const uint4*)(xp_bf + (size_t)gr*DD + ch*16);
      v0 = src[0]; v1 = src[1];
    }
    *(uint4*)&As[row][ch*16 + 0] = v0;
    *(uint4*)&As[row][ch*16 + 8] = v1;
  }
  __syncthreads();
  const int lane = t & 63, w = t >> 6;
  const int lr = lane & 15, lk = lane >> 4;
  f32x4 acc[25];
  #pragma unroll
  for (int i=0;i<25;i++) acc[i] = (f32x4){0.f,0.f,0.f,0.f};
  const short* wb = E_lay + (lr*4 + lk)*8;
  #pragma unroll
  for (int ks=0; ks<2; ++ks){
    bfrag a = *(const bfrag*)&As[w*16 + lr][ks*32 + lk*8];
    #pragma unroll
    for (int nt=0; nt<25; ++nt){
      bfrag bv = *(const bfrag*)(wb + (ks*25 + nt)*512);
      acc[nt] = __builtin_amdgcn_mfma_f32_16x16x32_bf16(a, bv, acc[nt], 0, 0, 0);
    }
  }
  const int row_t = t >> 2, q = t & 3;
  const int m = base + row_t;
  #pragma unroll
  for (int chunk=0; chunk<2; ++chunk){
    const int nt0 = chunk ? 13 : 0;
    const int nt1 = chunk ? 25 : 13;
    const int cb  = nt0*16;
    __syncthreads();
    #pragma unroll
    for (int nt=nt0; nt<nt1; ++nt){
      #pragma unroll
      for (int r=0; r<4; ++r)
        T[w*16 + lk*4 + r][nt*16 + lr - cb] = acc[nt][r];
    }
    __syncthreads();
    const int nk = chunk ? 12 : 13;
    if (m < NP){
      for (int k=0; k<nk; ++k){
        int c4 = q + 4*k;
        int col = cb + c4*4;
        float4 val = *(float4*)&T[row_t][c4*4];
        float4 cbv = *(const float4*)(cbias + col);
        val.x += cbv.x; val.y += cbv.y; val.z += cbv.z; val.w += cbv.w;
        *(float4*)(out + (size_t)m*V + col) = val;
      }
    }
  }
}

extern "C" void kernel_launch(void* const* d_in, const int* in_sizes, int n_in,
                              void* d_out, int out_size, void* d_ws, size_t ws_size,
                              hipStream_t stream){
  const float* emb   = (const float*)d_in[0];
  const float* cbias = (const float*)d_in[1];
  const float* Wci   = (const float*)d_in[2];
  const float* bci   = (const float*)d_in[3];
  const float* Wihc  = (const float*)d_in[4];
  const float* Whhc  = (const float*)d_in[5];
  const float* bihc  = (const float*)d_in[6];
  const float* bhhc  = (const float*)d_in[7];
  const float* Wihu  = (const float*)d_in[8];
  const float* Whhu  = (const float*)d_in[9];
  const float* bihu  = (const float*)d_in[10];
  const float* bhhu  = (const float*)d_in[11];
  const float* xpr   = (const float*)d_in[12];
  const int* y    = (const int*)d_in[13];
  const int* pt   = (const int*)d_in[14];
  const int* ct   = (const int*)d_in[15];
  const int* p2c  = (const int*)d_in[16];
  const int NP = in_sizes[13];
  const int NC = in_sizes[15];
  const int V  = in_sizes[1];
  const int NE = NC*4;

  char* w = (char*)d_ws;
  auto alloc = [&](size_t bytes)->char*{ char* p = w; w += (bytes + 255) & ~255ull; return p; };
  short* xp_bf = (short*)alloc((size_t)NP*DD*2);
  float* xph   = (float*)alloc((size_t)NP*DD*4);   // compacted by vlist position
  short* xc_bf = (short*)alloc((size_t)NC*DD*2);
  float* xch   = (float*)alloc((size_t)NC*DD*4);
  int*   tlist = (int*)alloc((size_t)4*NC*4);
  int*   ctr   = (int*)alloc(256);                 // [0..3]=cnt, [16]=nv
  short* Wc_lay= (short*)alloc((size_t)327680*2);
  short* Wu_lay= (short*)alloc((size_t)32768*2);
  short* E_lay = (short*)alloc((size_t)25600*2);
  int*   deg     = (int*)alloc((size_t)NP*4);
  int*   cursor  = (int*)alloc((size_t)NP*4);      // adjacent to deg
  int*   rowstart= (int*)alloc((size_t)NP*4);
  int*   elist   = (int*)alloc((size_t)NE*4);
  int*   bsum    = (int*)alloc(4096);
  int*   vlist   = (int*)alloc((size_t)NP*4);
  int* cnt  = ctr;
  int* cnt2 = ctr + 16;

  const int NB   = (NP + 255)/256;
  const int nbP4 = (NP*4 + 255)/256;
  const int nbC4 = (NC*4 + 255)/256;
  const int nbCl = (NC + 255)/256;
  const int nbCp = NB;
  const int nbE  = (NE + 255)/256;
  const int g_setup = 1280 + 128 + 100 + nbP4 + nbC4 + nbCl + nbCp + nbE;

  hipMemsetAsync(ctr, 0, 256, stream);
  hipMemsetAsync(deg, 0, (size_t)NP*8, stream);   // deg + cursor
  k_setup<<<g_setup, 256, 0, stream>>>(Wihc, Whhc, Wihu, Whhu, emb, Wci, bci, xpr,
                                       y, pt, ct, p2c,
                                       Wc_lay, Wu_lay, E_lay,
                                       xp_bf, xc_bf,
                                       tlist, cnt, vlist, cnt2, deg, NP, NC);
  k_blocksum<<<NB, 256, 0, stream>>>(deg, bsum, NP);
  k_scanblk<<<1, 1024, 0, stream>>>(bsum, NB);
  k_scanchunk<<<NB, 256, 0, stream>>>(deg, bsum, rowstart, NP);
  k_fill<<<nbE, 256, 0, stream>>>(p2c, rowstart, cursor, elist, NE);

  const int ctiles = (NC+63)/64 + 3;   // >= sum of per-type ceils
  const int num_iters = 2;             // fixed by the problem instance
  for (int it=0; it<num_iters; ++it){
    k_clause<<<ctiles, 256, 0, stream>>>(Wc_lay, bihc, bhhc, xp_bf, xc_bf, xch,
                                         p2c, tlist, cnt, NC, it==0);
    k_point<<<(NP+63)/64, 256, 0, stream>>>(Wu_lay, bihu, bhhu, xc_bf,
                                            rowstart, deg, elist, vlist, cnt2,
                                            xp_bf, xph, NP, it==0);
  }
  k_logits<<<(NP+63)/64, 256, 0, stream>>>(xp_bf, E_lay, cbias, (float*)d_out, NP, V);
}

// Round 8
// 441.146 us; speedup vs baseline: 3.4570x; 1.0089x over previous
//
#include <hip/hip_runtime.h>
#include <hip/hip_bf16.h>

#define DD 64
#define GG 256

typedef __attribute__((ext_vector_type(8))) __bf16 bfrag;   // 8 bf16 = 4 VGPRs
typedef __attribute__((ext_vector_type(4))) float f32x4;

__device__ __forceinline__ float sigmf(float x){ return 1.f/(1.f+__expf(-x)); }
__device__ __forceinline__ float tanhfast(float x){ return 1.f - 2.f/(__expf(2.f*x)+1.f); }
__device__ __forceinline__ short bf16c(float f){
  __hip_bfloat16 h = __float2bfloat16(f);
  return *reinterpret_cast<short*>(&h);
}

// ================= fused setup: weight permute + inits + classify + compact + deg ==========
// Weight layouts (fragment-order, MFMA B-operand = one 16B load):
//   Wc_lay[tp][ks10][nt16][lr16][lk4][e8], Wu_lay[ks4][nt16][lr][lk][e], E_lay[ks2][nt25][lr][lk][e]
__global__ void k_setup(
    const float* __restrict__ Wihc, const float* __restrict__ Whhc,
    const float* __restrict__ Wihu, const float* __restrict__ Whhu,
    const float* __restrict__ emb, const float* __restrict__ Wci,
    const float* __restrict__ bci, const float* __restrict__ xpr,
    const int* __restrict__ y, const int* __restrict__ pt,
    const int* __restrict__ ct, const int* __restrict__ p2c,
    short* __restrict__ Wc_lay, short* __restrict__ Wu_lay,
    short* __restrict__ E_lay,
    short* __restrict__ xp_bf, short* __restrict__ xc_bf,
    int* __restrict__ tlist, int* __restrict__ cnt,
    int* __restrict__ vlist, int* __restrict__ cnt2,
    int* __restrict__ deg, int NP, int NC)
{
  int b = blockIdx.x;
  const int t = threadIdx.x;
  if (b < 1280){                       // Wc_lay: 4*10*16*16*4*8 = 327680
    int idx = b*256 + t;
    int tp = idx / 81920, r = idx % 81920;
    int ks = r / 8192;  int r2 = r % 8192;
    int nt = r2 / 512;  int r3 = r2 % 512;
    int lr = r3 / 32;   int r4 = r3 % 32;
    int lk = r4 / 8,    e  = r4 % 8;
    int g = nt*16 + lr, k = ks*32 + lk*8 + e;
    float v = (k < 256) ? Wihc[((size_t)tp*256+g)*256 + k]
                        : Whhc[((size_t)tp*256+g)*64 + (k-256)];
    Wc_lay[idx] = bf16c(v);
    return;
  }
  b -= 1280;
  if (b < 128){                        // Wu_lay: 4*16*16*4*8 = 32768
    int idx = b*256 + t;
    int ks = idx / 8192; int r2 = idx % 8192;
    int nt = r2 / 512;   int r3 = r2 % 512;
    int lr = r3 / 32;    int r4 = r3 % 32;
    int lk = r4 / 8,     e  = r4 % 8;
    int g = nt*16 + lr, k = ks*32 + lk*8 + e;
    float v = (k < 64) ? Wihu[g*64 + k] : Whhu[g*64 + (k-64)];
    Wu_lay[idx] = bf16c(v);
    return;
  }
  b -= 128;
  if (b < 100){                        // E_lay: 2*25*16*4*8 = 25600
    int idx = b*256 + t;
    int ks = idx / 12800; int r = idx % 12800;
    int nt = r / 512;     int r3 = r % 512;
    int lr = r3 / 32;     int r4 = r3 % 32;
    int lk = r4 / 8,      e  = r4 % 8;
    int v = nt*16 + lr, k = ks*32 + lk*8 + e;
    E_lay[idx] = bf16c(emb[v*64 + k]);
    return;
  }
  b -= 100;
  int nbP4 = (NP*4 + 255) >> 8;
  if (b < nbP4){                       // init points (bf16 x_p only)
    int i = b*256 + t;
    if (i < NP*4){
      int p = i >> 2, ch = i & 3;
      const float* src = (pt[p]!=0) ? (emb + (size_t)y[p]*DD + ch*16)
                                    : (xpr + (size_t)p*DD + ch*16);
      short o[16];
      #pragma unroll
      for (int f4=0; f4<4; ++f4){
        float4 v = ((const float4*)src)[f4];
        o[f4*4+0]=bf16c(v.x); o[f4*4+1]=bf16c(v.y); o[f4*4+2]=bf16c(v.z); o[f4*4+3]=bf16c(v.w);
      }
      *(uint4*)(xp_bf + (size_t)p*DD + ch*16)     = *(uint4*)&o[0];
      *(uint4*)(xp_bf + (size_t)p*DD + ch*16 + 8) = *(uint4*)&o[8];
    }
    return;
  }
  b -= nbP4;
  int nbC4 = (NC*4 + 255) >> 8;
  if (b < nbC4){                       // init clauses (bf16 x_c only)
    int i = b*256 + t;
    if (i < NC*4){
      int c = i >> 2, ch = i & 3;
      short o[16];
      #pragma unroll
      for (int d=0; d<16; ++d) o[d] = bf16c(Wci[ch*16+d] + bci[ch*16+d]);
      *(uint4*)(xc_bf + (size_t)c*DD + ch*16)     = *(uint4*)&o[0];
      *(uint4*)(xc_bf + (size_t)c*DD + ch*16 + 8) = *(uint4*)&o[8];
    }
    return;
  }
  b -= nbC4;
  int nbCl = (NC + 255) >> 8;
  if (b < nbCl){                       // classify (wave-aggregated)
    int c = b*256 + t;
    int lane = t & 63;
    int tp = (c < NC) ? ct[c] : -1;
    unsigned long long lt = (lane == 63) ? ~0ull >> 1 : ((1ull << lane) - 1ull);
    #pragma unroll
    for (int ty=0; ty<4; ++ty){
      unsigned long long m = __ballot(tp==ty);
      if (m == 0ull) continue;
      int nw = __popcll(m), rank = __popcll(m & lt);
      int leader = __ffsll((long long)m) - 1;
      int base = 0;
      if (lane == leader) base = atomicAdd(cnt + ty, nw);
      base = __shfl(base, leader);
      if (tp == ty) tlist[ty*NC + base + rank] = c;
    }
    return;
  }
  b -= nbCl;
  int nbCp = (NP + 255) >> 8;
  if (b < nbCp){                       // compact variable points
    int p = b*256 + t;
    int lane = t & 63;
    bool var = (p < NP) && (pt[p]==0);
    unsigned long long lt = (lane == 63) ? ~0ull >> 1 : ((1ull << lane) - 1ull);
    unsigned long long m = __ballot(var);
    if (m){
      int nw = __popcll(m), rank = __popcll(m & lt);
      int leader = __ffsll((long long)m) - 1;
      int base = 0;
      if (lane == leader) base = atomicAdd(cnt2, nw);
      base = __shfl(base, leader);
      if (var) vlist[base + rank] = p;
    }
    return;
  }
  b -= nbCp;
  {                                    // degree count
    int e = b*256 + t;
    if (e < NC*4) atomicAdd(deg + p2c[e], 1);
  }
}

// ---------------- CSR: range allocation (wave-aggregated atomic) + fill ----------------
__global__ void k_rowstart(const int* __restrict__ deg, int* __restrict__ rowstart,
                           int* __restrict__ gtot, int NP){
  int p = blockIdx.x*256 + threadIdx.x;
  int lane = threadIdx.x & 63;
  int d = (p < NP) ? deg[p] : 0;
  int pre = d;
  #pragma unroll
  for (int off=1; off<64; off<<=1){
    int v = __shfl_up(pre, off);
    if (lane >= off) pre += v;
  }
  int tot = __shfl(pre, 63);
  int base = 0;
  if (lane == 63 && tot) base = atomicAdd(gtot, tot);
  base = __shfl(base, 63);
  if (p < NP) rowstart[p] = base + pre - d;
}
__global__ void k_fill(const int* __restrict__ p2c, const int* __restrict__ rowstart,
                       int* __restrict__ cursor, int* __restrict__ elist, int NE){
  int e = blockIdx.x*256 + threadIdx.x;
  if (e >= NE) return;
  int p = p2c[e];
  int pos = atomicAdd(cursor + p, 1);
  elist[rowstart[p] + pos] = e >> 2;   // clause index
}

// ---------------- clause LSTM: 1D-trimmed grid, barrier-free K-loop ----------------
__launch_bounds__(256)
__global__ void k_clause(const short* __restrict__ Wc_lay,
                         const float* __restrict__ bih, const float* __restrict__ bhh,
                         const short* __restrict__ xp_bf,
                         short* __restrict__ xc_bf, float* __restrict__ xch,
                         const int* __restrict__ p2c, const int* __restrict__ tlist,
                         const int* __restrict__ cnt, int NC, int first){
  __shared__ __align__(16) short As[64][328];
  int tp, n, base;
  {
    const int c0=cnt[0], c1=cnt[1], c2=cnt[2], c3=cnt[3];
    int b = blockIdx.x;
    const int t0=(c0+63)>>6;
    if (b < t0){ tp=0; n=c0; base=b<<6; }
    else { b-=t0; const int t1=(c1+63)>>6;
      if (b < t1){ tp=1; n=c1; base=b<<6; }
      else { b-=t1; const int t2=(c2+63)>>6;
        if (b < t2){ tp=2; n=c2; base=b<<6; }
        else { b-=t2; const int t3=(c3+63)>>6;
          if (b < t3){ tp=3; n=c3; base=b<<6; } else return; } } }
  }
  const int t = threadIdx.x;
  {
    int row = t >> 2, ch = t & 3;
    int idx = base + row;
    int c = (idx < n) ? tlist[tp*NC + idx] : -1;
    #pragma unroll
    for (int slot=0; slot<5; ++slot){
      uint4 v0 = make_uint4(0,0,0,0), v1 = make_uint4(0,0,0,0);
      const short* src = nullptr;
      if (c >= 0){
        if (slot < 4){
          if (!(tp==3 && slot==3)){          // midpoint zeros 4th slot
            int p = p2c[c*4 + slot];
            src = xp_bf + (size_t)p*DD + ch*16;
          }
        } else src = xc_bf + (size_t)c*DD + ch*16;
      }
      if (src){ v0 = *(const uint4*)src; v1 = *(const uint4*)(src+8); }
      *(uint4*)&As[row][slot*64 + ch*16 + 0] = v0;
      *(uint4*)&As[row][slot*64 + ch*16 + 8] = v1;
    }
  }
  __syncthreads();
  const int lane = t & 63, w = t >> 6;
  const int lr = lane & 15, lk = lane >> 4;
  f32x4 acc[16];
  #pragma unroll
  for (int i=0;i<16;i++) acc[i] = (f32x4){0.f,0.f,0.f,0.f};
  const short* wb = Wc_lay + (size_t)tp*81920 + (lr*4 + lk)*8;
  #pragma unroll
  for (int ks=0; ks<10; ++ks){
    bfrag a = *(const bfrag*)&As[w*16 + lr][ks*32 + lk*8];
    #pragma unroll
    for (int nt=0; nt<16; ++nt){
      bfrag bv = *(const bfrag*)(wb + (ks*16 + nt)*512);
      acc[nt] = __builtin_amdgcn_mfma_f32_16x16x32_bf16(a, bv, acc[nt], 0, 0, 0);
    }
  }
  #pragma unroll
  for (int r=0; r<4; ++r){
    int idx = base + w*16 + lk*4 + r;
    if (idx >= n) continue;
    int c = tlist[tp*NC + idx];
    #pragma unroll
    for (int q=0; q<4; ++q){
      int d = lr + 16*q;
      float gi = acc[q][r]    + bih[tp*GG + d]       + bhh[tp*GG + d];
      float gf = acc[4+q][r]  + bih[tp*GG + 64 + d]  + bhh[tp*GG + 64 + d];
      float gn = acc[8+q][r]  + bih[tp*GG + 128 + d] + bhh[tp*GG + 128 + d];
      float go = acc[12+q][r] + bih[tp*GG + 192 + d] + bhh[tp*GG + 192 + d];
      float cold = first ? 0.f : xch[(size_t)c*DD + d];
      float cn = sigmf(gf)*cold + sigmf(gi)*tanhfast(gn);
      float hn = sigmf(go)*tanhfast(cn);
      xc_bf[(size_t)c*DD + d] = bf16c(hn);
      xch[(size_t)c*DD + d]   = cn;
    }
  }
}

// ---------------- point LSTM: var points only; CSR gather fused; barrier-free ----------
__launch_bounds__(256)
__global__ void k_point(const short* __restrict__ Wu_lay,
                        const float* __restrict__ bihu, const float* __restrict__ bhhu,
                        const short* __restrict__ xc_bf,
                        const int* __restrict__ rowstart, const int* __restrict__ deg,
                        const int* __restrict__ elist, const int* __restrict__ vlist,
                        const int* __restrict__ nvp,
                        short* __restrict__ xp_bf, float* __restrict__ xph,
                        int NP, int first){
  const int nv = nvp[0];
  const int base = blockIdx.x*64;
  if (base >= nv) return;
  __shared__ __align__(16) short As[64][136];
  const int t = threadIdx.x;
  {
    int row = t >> 2, ch = t & 3;
    int idx = base + row;
    int gr = (idx < nv) ? vlist[idx] : -1;
    float s[16];
    #pragma unroll
    for (int z=0; z<16; ++z) s[z] = 0.f;
    uint4 xv0 = make_uint4(0,0,0,0), xv1 = make_uint4(0,0,0,0);
    if (gr >= 0){
      int rs = rowstart[gr], dg = deg[gr];
      for (int j=0; j<dg; ++j){
        int c = elist[rs + j];
        const uint4* xcp = (const uint4*)(xc_bf + (size_t)c*DD + ch*16);
        uint4 u0 = xcp[0], u1 = xcp[1];
        uint ua[8] = {u0.x,u0.y,u0.z,u0.w,u1.x,u1.y,u1.z,u1.w};
        #pragma unroll
        for (int i2=0;i2<8;i2++){
          s[i2*2]   += __uint_as_float(ua[i2] << 16);
          s[i2*2+1] += __uint_as_float(ua[i2] & 0xffff0000u);
        }
      }
      const uint4* xpp = (const uint4*)(xp_bf + (size_t)gr*DD + ch*16);
      xv0 = xpp[0]; xv1 = xpp[1];
    }
    short os[16];
    #pragma unroll
    for (int z=0; z<16; ++z) os[z] = bf16c(s[z]);
    *(uint4*)&As[row][ch*16 + 0] = *(uint4*)&os[0];
    *(uint4*)&As[row][ch*16 + 8] = *(uint4*)&os[8];
    *(uint4*)&As[row][64 + ch*16 + 0] = xv0;
    *(uint4*)&As[row][64 + ch*16 + 8] = xv1;
  }
  __syncthreads();
  const int lane = t & 63, w = t >> 6;
  const int lr = lane & 15, lk = lane >> 4;
  f32x4 acc[16];
  #pragma unroll
  for (int i=0;i<16;i++) acc[i] = (f32x4){0.f,0.f,0.f,0.f};
  const short* wb = Wu_lay + (lr*4 + lk)*8;
  #pragma unroll
  for (int ks=0; ks<4; ++ks){
    bfrag a = *(const bfrag*)&As[w*16 + lr][ks*32 + lk*8];
    #pragma unroll
    for (int nt=0; nt<16; ++nt){
      bfrag bv = *(const bfrag*)(wb + (ks*16 + nt)*512);
      acc[nt] = __builtin_amdgcn_mfma_f32_16x16x32_bf16(a, bv, acc[nt], 0, 0, 0);
    }
  }
  #pragma unroll
  for (int r=0; r<4; ++r){
    int idx = base + w*16 + lk*4 + r;
    if (idx >= nv) continue;
    int m = vlist[idx];
    #pragma unroll
    for (int q=0; q<4; ++q){
      int d = lr + 16*q;
      float gi = acc[q][r]    + bihu[d]       + bhhu[d];
      float gf = acc[4+q][r]  + bihu[64 + d]  + bhhu[64 + d];
      float gn = acc[8+q][r]  + bihu[128 + d] + bhhu[128 + d];
      float go = acc[12+q][r] + bihu[192 + d] + bhhu[192 + d];
      float cold = first ? 0.f : xph[(size_t)idx*DD + d];   // xph compacted by vlist pos
      float cn = sigmf(gf)*cold + sigmf(gi)*tanhfast(gn);
      float hn = sigmf(go)*tanhfast(cn);
      xp_bf[(size_t)m*DD + d] = bf16c(hn);
      xph[(size_t)idx*DD + d] = cn;
    }
  }
}

// ---------------- unified logits: wave-per-row contiguous stores ----------------
#define ST 212
__launch_bounds__(256)
__global__ void k_logits(const short* __restrict__ xp_bf, const short* __restrict__ E_lay,
                         const float* __restrict__ cbias,
                         float* __restrict__ out, int NP, int V){
  const int base = blockIdx.x*64;
  __shared__ __align__(16) char smem[64*ST*4];
  short (*As)[72] = (short (*)[72])smem;
  float (*T)[ST]  = (float (*)[ST])smem;   // overlays As after MFMA phase
  const int t = threadIdx.x;
  {
    int row = t >> 2, ch = t & 3;
    int gr = base + row;
    uint4 v0 = make_uint4(0,0,0,0), v1 = make_uint4(0,0,0,0);
    if (gr < NP){
      const uint4* src = (const uint4*)(xp_bf + (size_t)gr*DD + ch*16);
      v0 = src[0]; v1 = src[1];
    }
    *(uint4*)&As[row][ch*16 + 0] = v0;
    *(uint4*)&As[row][ch*16 + 8] = v1;
  }
  __syncthreads();
  const int lane = t & 63, w = t >> 6;
  const int lr = lane & 15, lk = lane >> 4;
  f32x4 acc[25];
  #pragma unroll
  for (int i=0;i<25;i++) acc[i] = (f32x4){0.f,0.f,0.f,0.f};
  const short* wb = E_lay + (lr*4 + lk)*8;
  #pragma unroll
  for (int ks=0; ks<2; ++ks){
    bfrag a = *(const bfrag*)&As[w*16 + lr][ks*32 + lk*8];
    #pragma unroll
    for (int nt=0; nt<25; ++nt){
      bfrag bv = *(const bfrag*)(wb + (ks*25 + nt)*512);
      acc[nt] = __builtin_amdgcn_mfma_f32_16x16x32_bf16(a, bv, acc[nt], 0, 0, 0);
    }
  }
  // epilogue: transpose (+cbias) in LDS, then wave-per-row contiguous float4 stores
  #pragma unroll
  for (int chunk=0; chunk<2; ++chunk){
    const int nt0 = chunk ? 13 : 0;
    const int nt1 = chunk ? 25 : 13;
    const int cb  = nt0*16;
    const int nc4 = chunk ? 48 : 52;     // float4 per row in this chunk
    __syncthreads();
    #pragma unroll
    for (int nt=nt0; nt<nt1; ++nt){
      float cbv = cbias[nt*16 + lr];
      #pragma unroll
      for (int r=0; r<4; ++r)
        T[w*16 + lk*4 + r][nt*16 + lr - cb] = acc[nt][r] + cbv;
    }
    __syncthreads();
    #pragma unroll
    for (int rr=0; rr<16; ++rr){
      int row = w*16 + rr;
      int m = base + row;
      if (m < NP && lane < nc4)
        *(float4*)(out + (size_t)m*V + cb + lane*4) = *(float4*)&T[row][lane*4];
    }
  }
}

extern "C" void kernel_launch(void* const* d_in, const int* in_sizes, int n_in,
                              void* d_out, int out_size, void* d_ws, size_t ws_size,
                              hipStream_t stream){
  const float* emb   = (const float*)d_in[0];
  const float* cbias = (const float*)d_in[1];
  const float* Wci   = (const float*)d_in[2];
  const float* bci   = (const float*)d_in[3];
  const float* Wihc  = (const float*)d_in[4];
  const float* Whhc  = (const float*)d_in[5];
  const float* bihc  = (const float*)d_in[6];
  const float* bhhc  = (const float*)d_in[7];
  const float* Wihu  = (const float*)d_in[8];
  const float* Whhu  = (const float*)d_in[9];
  const float* bihu  = (const float*)d_in[10];
  const float* bhhu  = (const float*)d_in[11];
  const float* xpr   = (const float*)d_in[12];
  const int* y    = (const int*)d_in[13];
  const int* pt   = (const int*)d_in[14];
  const int* ct   = (const int*)d_in[15];
  const int* p2c  = (const int*)d_in[16];
  const int NP = in_sizes[13];
  const int NC = in_sizes[15];
  const int V  = in_sizes[1];
  const int NE = NC*4;

  char* w = (char*)d_ws;
  auto alloc = [&](size_t bytes)->char*{ char* p = w; w += (bytes + 255) & ~255ull; return p; };
  short* xp_bf = (short*)alloc((size_t)NP*DD*2);
  float* xph   = (float*)alloc((size_t)NP*DD*4);   // compacted by vlist position
  short* xc_bf = (short*)alloc((size_t)NC*DD*2);
  float* xch   = (float*)alloc((size_t)NC*DD*4);
  int*   tlist = (int*)alloc((size_t)4*NC*4);
  short* Wc_lay= (short*)alloc((size_t)327680*2);
  short* Wu_lay= (short*)alloc((size_t)32768*2);
  short* E_lay = (short*)alloc((size_t)25600*2);
  // deg, cursor, ctr contiguous -> single memset
  int*   deg     = (int*)alloc((size_t)NP*4);      // NP*4 = 800000, 256B-aligned
  int*   cursor  = (int*)alloc((size_t)NP*4);
  int*   ctr     = (int*)alloc(256);               // [0..3]=cnt, [16]=nv, [17]=gtot
  int*   rowstart= (int*)alloc((size_t)NP*4);
  int*   elist   = (int*)alloc((size_t)NE*4);
  int*   vlist   = (int*)alloc((size_t)NP*4);
  int* cnt  = ctr;
  int* cnt2 = ctr + 16;
  int* gtot = ctr + 17;

  const int NB   = (NP + 255)/256;
  const int nbP4 = (NP*4 + 255)/256;
  const int nbC4 = (NC*4 + 255)/256;
  const int nbCl = (NC + 255)/256;
  const int nbCp = NB;
  const int nbE  = (NE + 255)/256;
  const int g_setup = 1280 + 128 + 100 + nbP4 + nbC4 + nbCl + nbCp + nbE;

  hipMemsetAsync(deg, 0, (size_t)NP*8 + 256, stream);   // deg + cursor + ctr
  k_setup<<<g_setup, 256, 0, stream>>>(Wihc, Whhc, Wihu, Whhu, emb, Wci, bci, xpr,
                                       y, pt, ct, p2c,
                                       Wc_lay, Wu_lay, E_lay,
                                       xp_bf, xc_bf,
                                       tlist, cnt, vlist, cnt2, deg, NP, NC);
  k_rowstart<<<NB, 256, 0, stream>>>(deg, rowstart, gtot, NP);
  k_fill<<<nbE, 256, 0, stream>>>(p2c, rowstart, cursor, elist, NE);

  const int ctiles = (NC+63)/64 + 3;   // >= sum of per-type ceils
  const int num_iters = 2;             // fixed by the problem instance
  for (int it=0; it<num_iters; ++it){
    k_clause<<<ctiles, 256, 0, stream>>>(Wc_lay, bihc, bhhc, xp_bf, xc_bf, xch,
                                         p2c, tlist, cnt, NC, it==0);
    k_point<<<(NP+63)/64, 256, 0, stream>>>(Wu_lay, bihu, bhhu, xc_bf,
                                            rowstart, deg, elist, vlist, cnt2,
                                            xp_bf, xph, NP, it==0);
  }
  k_logits<<<(NP+63)/64, 256, 0, stream>>>(xp_bf, E_lay, cbias, (float*)d_out, NP, V);
}